// Round 11
// baseline (504.873 us; speedup 1.0000x reference)
//
#include <hip/hip_runtime.h>

#define EMB 64
#define NBMAX 512      // max buckets (NB = ceil(N/512) = 293 for N=150000)
#define BCAP 8192      // bucket edge capacity (mean 6827, +16 sigma)
#define BSTRIDE 16384  // padded bucket region: BCAP + 512 nodes * 16 pad slots
#define NSLICE 8       // dim slices (8 dims = 16 B per node-slice), slice -> XCD

// ---------------- bf16 helpers ----------------

__device__ __forceinline__ unsigned short f2bf(float f) {   // round-to-nearest-even
    union { float f; unsigned u; } c; c.f = f;
    unsigned r = c.u + 0x7fffu + ((c.u >> 16) & 1u);
    return (unsigned short)(r >> 16);
}
__device__ __forceinline__ float bflo(unsigned u) {         // low bf16 -> f32
    union { unsigned u; float f; } c; c.u = u << 16; return c.f;
}
__device__ __forceinline__ float bfhi(unsigned u) {         // high bf16 -> f32
    union { unsigned u; float f; } c; c.u = u & 0xffff0000u; return c.f;
}
__device__ __forceinline__ unsigned pack2(float a, float b) {
    return (unsigned)f2bf(a) | ((unsigned)f2bf(b) << 16);
}

// ================= utility =================

__global__ void zero_u32_kernel(unsigned* __restrict__ p, int n) {
    int i = blockIdx.x * blockDim.x + threadIdx.x;
    if (i < n) p[i] = 0u;
}

// zero phantom row N of both y buffers, all 8 slices (4 words each)
__global__ void zero_dummy_kernel(unsigned* __restrict__ a, unsigned* __restrict__ b,
                                  int N, int Np1) {
    int t = threadIdx.x;            // 64 threads
    int s = (t & 31) >> 2, w = t & 3;
    size_t off = ((size_t)s * Np1 + N) * 4 + w;
    if (t < 32) a[off] = 0u; else b[off] = 0u;
}

// ================= feature fusion =================
// writes bf16 x into totT (transposed slices) and bf16 y = dis*x into y0

__global__ void fuse_users_kernel(const float* __restrict__ feat,       // [U,15]
                                  const int* __restrict__ cidx,
                                  const int* __restrict__ sidx,
                                  const float* __restrict__ emb_w,      // [U,64]
                                  const float* __restrict__ Wn,         // [64,12]
                                  const float* __restrict__ bn,
                                  const float* __restrict__ Wv,         // [64,3]
                                  const float* __restrict__ bv,
                                  const float* __restrict__ color_w,    // [22,64]
                                  const float* __restrict__ size_w,     // [18,64]
                                  const float* __restrict__ dis,        // [N]
                                  unsigned short* __restrict__ totT,    // [8][N][8] bf16
                                  unsigned short* __restrict__ y0,      // [8][Np1][8] bf16
                                  int U, int N, int Np1) {
    int t = blockIdx.x * blockDim.x + threadIdx.x;
    int u = t >> 6, d = t & 63;
    if (u >= U) return;
    const float* f = feat + (size_t)u * 15;
    float acc = emb_w[(size_t)u * EMB + d] + bn[d] + bv[d];
#pragma unroll
    for (int k = 0; k < 12; ++k) acc = fmaf(f[k], Wn[d * 12 + k], acc);
#pragma unroll
    for (int k = 0; k < 3; ++k) acc = fmaf(f[12 + k], Wv[d * 3 + k], acc);
    acc += color_w[(size_t)cidx[u] * EMB + d];
    acc += size_w[(size_t)sidx[u] * EMB + d];
    int s = d >> 3, dd = d & 7;
    totT[((size_t)s * N + u) * 8 + dd] = f2bf(acc);
    y0[((size_t)s * Np1 + u) * 8 + dd] = f2bf(acc * dis[u]);
}

__global__ void fuse_items_kernel(const float* __restrict__ feat,       // [I,17]
                                  const float* __restrict__ emb_w,      // [I,64]
                                  const float* __restrict__ Wn,         // [64,5]
                                  const float* __restrict__ bn,
                                  const float* __restrict__ Wv,         // [64,12]
                                  const float* __restrict__ bv,
                                  const float* __restrict__ dis,        // [N]
                                  unsigned short* __restrict__ totT,
                                  unsigned short* __restrict__ y0,
                                  int I, int U, int N, int Np1) {
    int t = blockIdx.x * blockDim.x + threadIdx.x;
    int i = t >> 6, d = t & 63;
    if (i >= I) return;
    const float* f = feat + (size_t)i * 17;
    float acc = emb_w[(size_t)i * EMB + d] + bn[d] + bv[d];
#pragma unroll
    for (int k = 0; k < 5; ++k) acc = fmaf(f[k], Wn[d * 5 + k], acc);
#pragma unroll
    for (int k = 0; k < 12; ++k) acc = fmaf(f[5 + k], Wv[d * 12 + k], acc);
    int n = U + i;
    int s = d >> 3, dd = d & 7;
    totT[((size_t)s * N + n) * 8 + dd] = f2bf(acc);
    y0[((size_t)s * Np1 + n) * 8 + dd] = f2bf(acc * dis[n]);
}

// ================= bucketed CSR build =================
// pass 1: partition edges into NB col-range buckets (packed row<<9 | col&511)

__global__ __launch_bounds__(256) void partition_kernel(
        const int* __restrict__ row, const int* __restrict__ col,
        unsigned* __restrict__ bcursor, unsigned* __restrict__ bucketbuf,
        int E, int NB) {
    __shared__ unsigned h[NBMAX];
    __shared__ unsigned wbase[NBMAX];
    const int t = threadIdx.x;
    const long chunk = (long)blockIdx.x * BCAP;

    for (int i = t; i < NB; i += 256) h[i] = 0u;
    __syncthreads();
    for (int it = 0; it < BCAP / 256; ++it) {
        long e = chunk + (long)it * 256 + t;
        if (e < E) atomicAdd(&h[((unsigned)col[e]) >> 9], 1u);
    }
    __syncthreads();
    for (int i = t; i < NB; i += 256) {
        unsigned c = h[i];
        wbase[i] = c ? atomicAdd(&bcursor[i], c) : 0u;
    }
    __syncthreads();
    for (int i = t; i < NB; i += 256) h[i] = 0u;
    __syncthreads();
    for (int it = 0; it < BCAP / 256; ++it) {
        long e = chunk + (long)it * 256 + t;
        if (e < E) {
            unsigned c = (unsigned)col[e];
            unsigned b = c >> 9;
            unsigned lpos = atomicAdd(&h[b], 1u);
            unsigned pos = wbase[b] + lpos;
            if (pos < BCAP)
                bucketbuf[(size_t)b * BCAP + pos] = (((unsigned)row[e]) << 9) | (c & 511u);
        }
    }
}

// pass 2: one WG per bucket -> meta (pad-16 lists), dis, srcidx (pre-shifted
// word offsets r*4 + phantom pads), degree-class counts

__global__ __launch_bounds__(256) void bucket_csr_kernel(
        const unsigned* __restrict__ bcursor,   // final per-bucket counts
        const unsigned* __restrict__ bucketbuf,
        uint4* __restrict__ meta,               // [N] {beg,end,dis_bits,0}
        float* __restrict__ dis, unsigned* __restrict__ srcidx,
        unsigned* __restrict__ clsCnt,          // [64] global degree-class counts
        int N, int NB) {
    const int b = blockIdx.x;
    const int t = threadIdx.x;
    __shared__ unsigned hist[512];
    __shared__ unsigned ps[256];
    __shared__ unsigned cls[64];

    const unsigned base = (unsigned)b * BSTRIDE;
    unsigned cntb = bcursor[b];
    if (cntb > BCAP) cntb = BCAP;

    hist[2 * t] = 0u; hist[2 * t + 1] = 0u;
    if (t < 64) cls[t] = 0u;
    __syncthreads();
    const unsigned* buf = bucketbuf + (size_t)b * BCAP;
    for (unsigned j = t; j < cntb; j += 256) atomicAdd(&hist[buf[j] & 511u], 1u);
    __syncthreads();

    unsigned h0 = hist[2 * t], h1 = hist[2 * t + 1];
    unsigned c0p = (h0 + 15u) & ~15u, c1p = (h1 + 15u) & ~15u;  // pad to mult of 16
    ps[t] = c0p + c1p;
    __syncthreads();
    for (int off = 1; off < 256; off <<= 1) {
        unsigned y = (t >= off) ? ps[t - off] : 0u;
        __syncthreads();
        ps[t] += y;
        __syncthreads();
    }
    unsigned pexcl = ps[t] - (c0p + c1p);
    unsigned beg0 = base + pexcl, beg1 = beg0 + c0p;

    int n0 = (b << 9) + 2 * t, n1 = n0 + 1;
    if (n0 < N) {
        float dv = h0 ? rsqrtf((float)h0) : 0.f;
        meta[n0] = make_uint4(beg0, beg0 + c0p, __float_as_uint(dv), 0u);
        dis[n0] = dv;
        atomicAdd(&cls[min(c0p >> 4, 63u)], 1u);
        for (unsigned k = h0; k < c0p; ++k) srcidx[beg0 + k] = ((unsigned)N) << 2;
    }
    if (n1 < N) {
        float dv = h1 ? rsqrtf((float)h1) : 0.f;
        meta[n1] = make_uint4(beg1, beg1 + c1p, __float_as_uint(dv), 0u);
        dis[n1] = dv;
        atomicAdd(&cls[min(c1p >> 4, 63u)], 1u);
        for (unsigned k = h1; k < c1p; ++k) srcidx[beg1 + k] = ((unsigned)N) << 2;
    }
    __syncthreads();

    if (t < 64 && cls[t]) atomicAdd(&clsCnt[t], cls[t]);
    // repurpose hist as scatter cursors
    hist[2 * t] = beg0; hist[2 * t + 1] = beg1;
    __syncthreads();
    for (unsigned j = t; j < cntb; j += 256) {
        unsigned p = buf[j];
        unsigned pos = atomicAdd(&hist[p & 511u], 1u);
        srcidx[pos] = (p >> 9) << 2;   // u32 word offset of source row-slice
    }
}

// exclusive scan of the 64 class counts -> clsBase

__global__ void cls_scan_kernel(const unsigned* __restrict__ clsCnt,
                                unsigned* __restrict__ clsBase) {
    __shared__ unsigned sh[64];
    int t = threadIdx.x;
    if (t < 64) sh[t] = clsCnt[t];
    __syncthreads();
    if (t == 0) {
        unsigned run = 0;
        for (int i = 0; i < 64; ++i) { unsigned v = sh[i]; sh[i] = run; run += v; }
    }
    __syncthreads();
    if (t < 64) clsBase[t] = sh[t];
}

// counting-sort node ids by degree class into order[] (LDS-aggregated)

__global__ __launch_bounds__(256) void order_fill_kernel(
        const uint4* __restrict__ meta,
        const unsigned* __restrict__ clsBase, unsigned* __restrict__ clsCur,
        unsigned* __restrict__ order, int N) {
    __shared__ unsigned h[64], wb[64];
    int t = threadIdx.x;
    int n = blockIdx.x * 256 + t;
    if (t < 64) h[t] = 0u;
    __syncthreads();
    unsigned c = 0, lpos = 0;
    bool valid = n < N;
    if (valid) {
        uint4 md = meta[n];
        c = min((md.y - md.x) >> 4, 63u);
        lpos = atomicAdd(&h[c], 1u);
    }
    __syncthreads();
    if (t < 64) wb[t] = h[t] ? atomicAdd(&clsCur[t], h[t]) : 0u;
    __syncthreads();
    if (valid) order[clsBase[c] + wb[c] + lpos] = (unsigned)n;
}

// ================= propagation: 8-slice XCD-local, 4-node waves =================
// slice s = blockIdx&7 -> XCD s (round-robin). Slice region [s][Np1][4] u32 =
// 2.4 MB -> resident in that XCD's L2. Wave = 4 nodes x 16 edge-lanes; lane
// (sub,q) loads the full 16 B slice of edge q of node sub -> one wave-load =
// 64 row-slices (1 KB). Degree-sorted order makes sub trip counts equal.
// Butterfly-reduce over the 16 q-lanes; q==0 RMWs bf16 totT, q==1 writes ynext.

__global__ __launch_bounds__(256) void gather_slice_kernel(
        const unsigned* __restrict__ order, const uint4* __restrict__ meta,
        const unsigned* __restrict__ src,      // [8][Np1][4] u32 (bf16x2)
        const unsigned* __restrict__ srcidx,   // word offsets r*4
        unsigned* __restrict__ ynext,          // [8][Np1][4]
        unsigned* __restrict__ totT,           // [8][N][4] bf16x2 RMW
        int N, int Np1, int store) {
    const int s = blockIdx.x & 7;
    const int g = blockIdx.x >> 3;
    const int lane = threadIdx.x & 63;
    const int q = lane & 15;
    const int slot = g * 16 + ((threadIdx.x >> 6) << 2) + (lane >> 4);
    if (slot >= N) return;
    const int n = (int)order[slot];
    const uint4 md = meta[n];
    const unsigned* sbase = src + (size_t)s * Np1 * 4u;
    float a0 = 0.f, a1 = 0.f, a2 = 0.f, a3 = 0.f,
          a4 = 0.f, a5 = 0.f, a6 = 0.f, a7 = 0.f;
    for (unsigned j = md.x + (unsigned)q; j < md.y; j += 16u) {
        unsigned r = srcidx[j];
        uint4 u = *reinterpret_cast<const uint4*>(sbase + r);
        a0 += bflo(u.x); a1 += bfhi(u.x);
        a2 += bflo(u.y); a3 += bfhi(u.y);
        a4 += bflo(u.z); a5 += bfhi(u.z);
        a6 += bflo(u.w); a7 += bfhi(u.w);
    }
#pragma unroll
    for (int mask = 1; mask <= 8; mask <<= 1) {
        a0 += __shfl_xor(a0, mask); a1 += __shfl_xor(a1, mask);
        a2 += __shfl_xor(a2, mask); a3 += __shfl_xor(a3, mask);
        a4 += __shfl_xor(a4, mask); a5 += __shfl_xor(a5, mask);
        a6 += __shfl_xor(a6, mask); a7 += __shfl_xor(a7, mask);
    }
    const float dn = __uint_as_float(md.z);
    if (q == 0) {            // RMW running total (bf16, slice-local region)
        size_t o = ((size_t)s * N + n) * 4u;
        uint4 tv = *reinterpret_cast<const uint4*>(totT + o);
        uint4 nv;
        nv.x = pack2(bflo(tv.x) + dn * a0, bfhi(tv.x) + dn * a1);
        nv.y = pack2(bflo(tv.y) + dn * a2, bfhi(tv.y) + dn * a3);
        nv.z = pack2(bflo(tv.z) + dn * a4, bfhi(tv.z) + dn * a5);
        nv.w = pack2(bflo(tv.w) + dn * a6, bfhi(tv.w) + dn * a7);
        *reinterpret_cast<uint4*>(totT + o) = nv;
    } else if (q == 1 && store) {   // next-layer y = dis * a = dn^2 * sum
        float d2 = dn * dn;
        size_t o = ((size_t)s * Np1 + n) * 4u;
        uint4 pk;
        pk.x = pack2(d2 * a0, d2 * a1);
        pk.y = pack2(d2 * a2, d2 * a3);
        pk.z = pack2(d2 * a4, d2 * a5);
        pk.w = pack2(d2 * a6, d2 * a7);
        *reinterpret_cast<uint4*>(ynext + o) = pk;
    }
}

// ================= final untranspose: out[n][d] = totT[d>>3][n][d&7] / 4 ====

__global__ void untranspose_kernel(const unsigned* __restrict__ totT,
                                   float2* __restrict__ out2, int N) {
    int t = blockIdx.x * blockDim.x + threadIdx.x;
    int n = t >> 5;
    if (n >= N) return;
    unsigned w = (unsigned)(t & 31);          // dim-pair id; slice = w>>2, word = w&3
    unsigned u = totT[(((size_t)(w >> 2) * N + n) * 4) + (w & 3)];
    float2 v;
    v.x = bflo(u) * 0.25f;
    v.y = bfhi(u) * 0.25f;
    out2[(size_t)t] = v;                      // == out2[n*32 + w], coalesced
}

// ================= launch =================

extern "C" void kernel_launch(void* const* d_in, const int* in_sizes, int n_in,
                              void* d_out, int out_size, void* d_ws, size_t ws_size,
                              hipStream_t stream) {
    const int*   edge       = (const int*)d_in[0];
    const float* user_feat  = (const float*)d_in[1];
    const int*   cidx       = (const int*)d_in[2];
    const int*   sidx       = (const int*)d_in[3];
    const float* item_feat  = (const float*)d_in[4];
    const float* user_emb_w = (const float*)d_in[5];
    const float* item_emb_w = (const float*)d_in[6];
    const float* uWn        = (const float*)d_in[7];
    const float* ubn        = (const float*)d_in[8];
    const float* uWv        = (const float*)d_in[9];
    const float* ubv        = (const float*)d_in[10];
    const float* color_w    = (const float*)d_in[11];
    const float* size_w     = (const float*)d_in[12];
    const float* iWn        = (const float*)d_in[13];
    const float* ibn        = (const float*)d_in[14];
    const float* iWv        = (const float*)d_in[15];
    const float* ibv        = (const float*)d_in[16];

    const int E = in_sizes[0] / 2;
    const int U = in_sizes[5] / EMB;
    const int I = in_sizes[6] / EMB;
    const int N = U + I;
    const int Np1 = N + 1;
    const int NB = (N + 511) >> 9;     // 293 buckets

    const int* row = edge;
    const int* col = edge + E;

    // workspace layout (u32 units)
    unsigned* yA      = (unsigned*)d_ws;                    // [8*Np1*4] bf16x2 sliced
    unsigned* yB      = yA + (size_t)NSLICE * Np1 * 4;      // [8*Np1*4]
    unsigned* bucketbuf = yB;                               // [NB*BCAP] aliases yB
    unsigned* totT    = yB + (size_t)NSLICE * Np1 * 4;      // [8*N*4] bf16x2 sliced
    unsigned* srcidx  = totT + (size_t)NSLICE * N * 4;      // [NB*BSTRIDE]
    uint4*    meta    = (uint4*)(srcidx + (size_t)NB * BSTRIDE);  // [N]
    float*    dis     = (float*)(meta + N);                 // [N]
    unsigned* bcursor = (unsigned*)(dis + N);               // [NB]
    unsigned* clsCnt  = bcursor + NB;                       // [64]
    unsigned* clsCur  = clsCnt + 64;                        // [64]
    unsigned* clsBase = clsCur + 64;                        // [64]
    unsigned* order   = clsBase + 64;                       // [N]

    const int TB = 256;

    // 1. CSR build (also produces meta/dis + degree-class counts)
    zero_u32_kernel<<<(NB + 128 + TB - 1) / TB, TB, 0, stream>>>(bcursor, NB + 128);
    const int gP = (E + BCAP - 1) / BCAP;
    partition_kernel<<<gP, TB, 0, stream>>>(row, col, bcursor, bucketbuf, E, NB);
    bucket_csr_kernel<<<NB, TB, 0, stream>>>(bcursor, bucketbuf, meta, dis,
                                             srcidx, clsCnt, N, NB);
    // degree-class scheduling order
    cls_scan_kernel<<<1, 64, 0, stream>>>(clsCnt, clsBase);
    order_fill_kernel<<<(N + TB - 1) / TB, TB, 0, stream>>>(meta, clsBase,
                                                            clsCur, order, N);
    // phantom row N of both y buffers = 0 (after bucketbuf's lifetime ends)
    zero_dummy_kernel<<<1, 64, 0, stream>>>(yA, yB, N, Np1);

    // 2. fuse features -> totT (bf16 x), yA (bf16 dis*x), both slice-transposed
    {
        int gU = (int)(((long)U * EMB + TB - 1) / TB);
        fuse_users_kernel<<<gU, TB, 0, stream>>>(user_feat, cidx, sidx, user_emb_w,
                                                 uWn, ubn, uWv, ubv, color_w, size_w,
                                                 dis, (unsigned short*)totT,
                                                 (unsigned short*)yA, U, N, Np1);
        int gI = (int)(((long)I * EMB + TB - 1) / TB);
        fuse_items_kernel<<<gI, TB, 0, stream>>>(item_feat, item_emb_w,
                                                 iWn, ibn, iWv, ibv,
                                                 dis, (unsigned short*)totT,
                                                 (unsigned short*)yA, I, U, N, Np1);
    }

    // 3. three propagation layers, slice-parallel (slice -> XCD), totT fused
    const int gG = 8 * ((N + 15) / 16);
    gather_slice_kernel<<<gG, TB, 0, stream>>>(order, meta, yA, srcidx, yB, totT,
                                               N, Np1, 1);
    gather_slice_kernel<<<gG, TB, 0, stream>>>(order, meta, yB, srcidx, yA, totT,
                                               N, Np1, 1);
    gather_slice_kernel<<<gG, TB, 0, stream>>>(order, meta, yA, srcidx, yB, totT,
                                               N, Np1, 0);

    // 4. untranspose + /4 into d_out
    const long tU = (long)N * 32;
    untranspose_kernel<<<(int)((tU + TB - 1) / TB), TB, 0, stream>>>(totT,
                                                                     (float2*)d_out, N);

    (void)n_in; (void)out_size; (void)ws_size;
}

// Round 12
// 306.271 us; speedup vs baseline: 1.6485x; 1.6485x over previous
//
#include <hip/hip_runtime.h>

#define EMB 64
#define NBMAX 512      // max buckets (NB = ceil(N/512) = 293 for N=150000)
#define BCAP 8192      // bucket edge capacity (mean 6827, +16 sigma)
#define BSTRIDE 12288  // padded bucket region: BCAP + 512 nodes * 8 pad slots
#define CHUNK 2048     // edges per partition WG (977 blocks -> ~4/CU TLP)

// ---------------- bf16 helpers ----------------

__device__ __forceinline__ unsigned short f2bf(float f) {   // round-to-nearest-even
    union { float f; unsigned u; } c; c.f = f;
    unsigned r = c.u + 0x7fffu + ((c.u >> 16) & 1u);
    return (unsigned short)(r >> 16);
}
__device__ __forceinline__ float bflo(unsigned u) {         // low bf16 -> f32
    union { unsigned u; float f; } c; c.u = u << 16; return c.f;
}
__device__ __forceinline__ float bfhi(unsigned u) {         // high bf16 -> f32
    union { unsigned u; float f; } c; c.u = u & 0xffff0000u; return c.f;
}

// ================= init: zero bcursor/cls + phantom rows =================

__global__ void init_kernel(unsigned* __restrict__ p, int nz,
                            unsigned* __restrict__ dummyA,
                            unsigned* __restrict__ dummyB) {
    int i = blockIdx.x * blockDim.x + threadIdx.x;
    if (i < nz) p[i] = 0u;
    if (blockIdx.x == 0) {
        int t = threadIdx.x;
        if (t < 32) dummyA[t] = 0u;
        else if (t < 64) dummyB[t - 32] = 0u;
    }
}

// ================= feature fusion =================
// writes plain x into total (=d_out) and dis-premultiplied bf16 y into y0

__global__ void fuse_users_kernel(const float* __restrict__ feat,       // [U,15]
                                  const int* __restrict__ cidx,
                                  const int* __restrict__ sidx,
                                  const float* __restrict__ emb_w,      // [U,64]
                                  const float* __restrict__ Wn,         // [64,12]
                                  const float* __restrict__ bn,
                                  const float* __restrict__ Wv,         // [64,3]
                                  const float* __restrict__ bv,
                                  const float* __restrict__ color_w,    // [22,64]
                                  const float* __restrict__ size_w,     // [18,64]
                                  const float* __restrict__ dis,        // [N]
                                  float* __restrict__ total,            // [N,64]
                                  unsigned short* __restrict__ y0,      // [(N+1),64] bf16
                                  int U) {
    int t = blockIdx.x * blockDim.x + threadIdx.x;
    int u = t >> 6, d = t & 63;
    if (u >= U) return;
    const float* f = feat + (size_t)u * 15;
    float acc = emb_w[(size_t)u * EMB + d] + bn[d] + bv[d];
#pragma unroll
    for (int k = 0; k < 12; ++k) acc = fmaf(f[k], Wn[d * 12 + k], acc);
#pragma unroll
    for (int k = 0; k < 3; ++k) acc = fmaf(f[12 + k], Wv[d * 3 + k], acc);
    acc += color_w[(size_t)cidx[u] * EMB + d];
    acc += size_w[(size_t)sidx[u] * EMB + d];
    size_t o = (size_t)u * EMB + d;
    total[o] = acc;
    y0[o] = f2bf(acc * dis[u]);
}

__global__ void fuse_items_kernel(const float* __restrict__ feat,       // [I,17]
                                  const float* __restrict__ emb_w,      // [I,64]
                                  const float* __restrict__ Wn,         // [64,5]
                                  const float* __restrict__ bn,
                                  const float* __restrict__ Wv,         // [64,12]
                                  const float* __restrict__ bv,
                                  const float* __restrict__ dis,        // [N]
                                  float* __restrict__ total,
                                  unsigned short* __restrict__ y0,
                                  int I, int U) {
    int t = blockIdx.x * blockDim.x + threadIdx.x;
    int i = t >> 6, d = t & 63;
    if (i >= I) return;
    const float* f = feat + (size_t)i * 17;
    float acc = emb_w[(size_t)i * EMB + d] + bn[d] + bv[d];
#pragma unroll
    for (int k = 0; k < 5; ++k) acc = fmaf(f[k], Wn[d * 5 + k], acc);
#pragma unroll
    for (int k = 0; k < 12; ++k) acc = fmaf(f[5 + k], Wv[d * 12 + k], acc);
    int n = U + i;
    size_t o = (size_t)n * EMB + d;
    total[o] = acc;
    y0[o] = f2bf(acc * dis[n]);
}

// ================= bucketed CSR build =================
// pass 1: partition edges into NB col-range buckets (packed row<<9 | col&511)

__global__ __launch_bounds__(256) void partition_kernel(
        const int* __restrict__ row, const int* __restrict__ col,
        unsigned* __restrict__ bcursor, unsigned* __restrict__ bucketbuf,
        int E, int NB) {
    __shared__ unsigned h[NBMAX];
    __shared__ unsigned wbase[NBMAX];
    const int t = threadIdx.x;
    const long chunk = (long)blockIdx.x * CHUNK;

    for (int i = t; i < NB; i += 256) h[i] = 0u;
    __syncthreads();
    for (int it = 0; it < CHUNK / 256; ++it) {
        long e = chunk + (long)it * 256 + t;
        if (e < E) atomicAdd(&h[((unsigned)col[e]) >> 9], 1u);
    }
    __syncthreads();
    for (int i = t; i < NB; i += 256) {
        unsigned c = h[i];
        wbase[i] = c ? atomicAdd(&bcursor[i], c) : 0u;
    }
    __syncthreads();
    for (int i = t; i < NB; i += 256) h[i] = 0u;
    __syncthreads();
    for (int it = 0; it < CHUNK / 256; ++it) {
        long e = chunk + (long)it * 256 + t;
        if (e < E) {
            unsigned c = (unsigned)col[e];
            unsigned b = c >> 9;
            unsigned lpos = atomicAdd(&h[b], 1u);
            unsigned pos = wbase[b] + lpos;
            if (pos < BCAP)
                bucketbuf[(size_t)b * BCAP + pos] = (((unsigned)row[e]) << 9) | (c & 511u);
        }
    }
}

// pass 2: one WG per bucket -> meta (pad-8 lists), dis, srcidx (pre-shifted
// word offsets r*32 + phantom pads), degree-class counts

__global__ __launch_bounds__(256) void bucket_csr_kernel(
        const unsigned* __restrict__ bcursor,   // final per-bucket counts
        const unsigned* __restrict__ bucketbuf,
        uint4* __restrict__ meta,               // [N] {beg,end,dis_bits,0}
        float* __restrict__ dis, unsigned* __restrict__ srcidx,
        unsigned* __restrict__ clsCnt,          // [64] global degree-class counts
        int N, int NB) {
    const int b = blockIdx.x;
    const int t = threadIdx.x;
    __shared__ unsigned hist[512];
    __shared__ unsigned ps[256];
    __shared__ unsigned cls[64];

    const unsigned base = (unsigned)b * BSTRIDE;
    unsigned cntb = bcursor[b];
    if (cntb > BCAP) cntb = BCAP;

    hist[2 * t] = 0u; hist[2 * t + 1] = 0u;
    if (t < 64) cls[t] = 0u;
    __syncthreads();
    const unsigned* buf = bucketbuf + (size_t)b * BCAP;
    for (unsigned j = t; j < cntb; j += 256) atomicAdd(&hist[buf[j] & 511u], 1u);
    __syncthreads();

    unsigned h0 = hist[2 * t], h1 = hist[2 * t + 1];
    unsigned c0p = (h0 + 7u) & ~7u, c1p = (h1 + 7u) & ~7u;   // pad to multiple of 8
    ps[t] = c0p + c1p;
    __syncthreads();
    for (int off = 1; off < 256; off <<= 1) {
        unsigned y = (t >= off) ? ps[t - off] : 0u;
        __syncthreads();
        ps[t] += y;
        __syncthreads();
    }
    unsigned pexcl = ps[t] - (c0p + c1p);
    unsigned beg0 = base + pexcl, beg1 = beg0 + c0p;

    int n0 = (b << 9) + 2 * t, n1 = n0 + 1;
    if (n0 < N) {
        float dv = h0 ? rsqrtf((float)h0) : 0.f;
        meta[n0] = make_uint4(beg0, beg0 + c0p, __float_as_uint(dv), 0u);
        dis[n0] = dv;
        atomicAdd(&cls[min(c0p >> 3, 63u)], 1u);
        for (unsigned k = h0; k < c0p; ++k) srcidx[beg0 + k] = ((unsigned)N) << 5;
    }
    if (n1 < N) {
        float dv = h1 ? rsqrtf((float)h1) : 0.f;
        meta[n1] = make_uint4(beg1, beg1 + c1p, __float_as_uint(dv), 0u);
        dis[n1] = dv;
        atomicAdd(&cls[min(c1p >> 3, 63u)], 1u);
        for (unsigned k = h1; k < c1p; ++k) srcidx[beg1 + k] = ((unsigned)N) << 5;
    }
    __syncthreads();

    if (t < 64 && cls[t]) atomicAdd(&clsCnt[t], cls[t]);
    // repurpose hist as scatter cursors
    hist[2 * t] = beg0; hist[2 * t + 1] = beg1;
    __syncthreads();
    for (unsigned j = t; j < cntb; j += 256) {
        unsigned p = buf[j];
        unsigned pos = atomicAdd(&hist[p & 511u], 1u);
        srcidx[pos] = (p >> 9) << 5;   // u32 word offset of source row
    }
}

// exclusive scan of the 64 class counts -> clsBase

__global__ void cls_scan_kernel(const unsigned* __restrict__ clsCnt,
                                unsigned* __restrict__ clsBase) {
    __shared__ unsigned sh[64];
    int t = threadIdx.x;
    if (t < 64) sh[t] = clsCnt[t];
    __syncthreads();
    if (t == 0) {
        unsigned run = 0;
        for (int i = 0; i < 64; ++i) { unsigned v = sh[i]; sh[i] = run; run += v; }
    }
    __syncthreads();
    if (t < 64) clsBase[t] = sh[t];
}

// counting-sort node ids by degree class into order[] (LDS-aggregated)

__global__ __launch_bounds__(256) void order_fill_kernel(
        const uint4* __restrict__ meta,
        const unsigned* __restrict__ clsBase, unsigned* __restrict__ clsCur,
        unsigned* __restrict__ order, int N) {
    __shared__ unsigned h[64], wb[64];
    int t = threadIdx.x;
    int n = blockIdx.x * 256 + t;
    if (t < 64) h[t] = 0u;
    __syncthreads();
    unsigned c = 0, lpos = 0;
    bool valid = n < N;
    if (valid) {
        uint4 md = meta[n];
        c = min((md.y - md.x) >> 3, 63u);
        lpos = atomicAdd(&h[c], 1u);
    }
    __syncthreads();
    if (t < 64) wb[t] = h[t] ? atomicAdd(&clsCur[t], h[t]) : 0u;
    __syncthreads();
    if (valid) order[clsBase[c] + wb[c] + lpos] = (unsigned)n;
}

// ================= propagation =================
// y rows viewed as 32 u32 words (bf16x2). One wave per node (degree-sorted via
// order[]). lane = (q, m): lane's uint4 idx load srcidx[j+4q] covers its OWN
// four edges (4q..4q+3) -> ONE VMEM instr covers all 16 edges of the group
// (summation commutative, regrouping free). m = lane&15 covers dims 4m..4m+3
// via uint2 row loads (one wave-load = 4 source rows). srcidx values are
// pre-shifted word offsets (r*32). 16-edge main loop + 8-edge tail.

__global__ __launch_bounds__(256) void gather_propagate_kernel(
        const unsigned* __restrict__ order, const uint4* __restrict__ meta,
        const unsigned* __restrict__ src,   // [(N+1)*32]
        const unsigned* __restrict__ srcidx,
        unsigned* __restrict__ ynext,      // [(N+1)*32]
        float4* __restrict__ total4,       // [N*16]
        float scale, int N, int store) {
    int slot = blockIdx.x * 4 + (threadIdx.x >> 6);
    if (slot >= N) return;
    int n = (int)order[slot];
    uint4 md = meta[n];
    unsigned beg = md.x, endp = md.y;
    float dn = __uint_as_float(md.z);
    int lane = threadIdx.x & 63;
    unsigned q = (unsigned)(lane >> 4);
    unsigned m2 = (unsigned)(lane & 15) * 2u;
    float s0 = 0.f, s1 = 0.f, s2 = 0.f, s3 = 0.f;
    unsigned j = beg;
    for (; j + 16 <= endp; j += 16) {
        uint4 iv = *reinterpret_cast<const uint4*>(&srcidx[j + 4u * q]);
        uint2 ua = *reinterpret_cast<const uint2*>(&src[iv.x + m2]);
        uint2 ub = *reinterpret_cast<const uint2*>(&src[iv.y + m2]);
        uint2 uc = *reinterpret_cast<const uint2*>(&src[iv.z + m2]);
        uint2 ud = *reinterpret_cast<const uint2*>(&src[iv.w + m2]);
        s0 += (bflo(ua.x) + bflo(ub.x)) + (bflo(uc.x) + bflo(ud.x));
        s1 += (bfhi(ua.x) + bfhi(ub.x)) + (bfhi(uc.x) + bfhi(ud.x));
        s2 += (bflo(ua.y) + bflo(ub.y)) + (bflo(uc.y) + bflo(ud.y));
        s3 += (bfhi(ua.y) + bfhi(ub.y)) + (bfhi(uc.y) + bfhi(ud.y));
    }
    if (j < endp) {   // 8-edge tail (lists are multiples of 8)
        uint2 iv = *reinterpret_cast<const uint2*>(&srcidx[j + 2u * q]);
        uint2 ua = *reinterpret_cast<const uint2*>(&src[iv.x + m2]);
        uint2 ub = *reinterpret_cast<const uint2*>(&src[iv.y + m2]);
        s0 += bflo(ua.x) + bflo(ub.x);
        s1 += bfhi(ua.x) + bfhi(ub.x);
        s2 += bflo(ua.y) + bflo(ub.y);
        s3 += bfhi(ua.y) + bfhi(ub.y);
    }
    // combine the four edge-subset groups
    s0 += __shfl_xor(s0, 16); s0 += __shfl_xor(s0, 32);
    s1 += __shfl_xor(s1, 16); s1 += __shfl_xor(s1, 32);
    s2 += __shfl_xor(s2, 16); s2 += __shfl_xor(s2, 32);
    s3 += __shfl_xor(s3, 16); s3 += __shfl_xor(s3, 32);
    if (lane < 16) {
        float a0 = dn * s0, a1 = dn * s1, a2 = dn * s2, a3 = dn * s3;
        size_t o4 = (size_t)n * 16 + (m2 >> 1);
        float4 tv = total4[o4];
        total4[o4] = make_float4((tv.x + a0) * scale, (tv.y + a1) * scale,
                                 (tv.z + a2) * scale, (tv.w + a3) * scale);
        if (store) {
            uint2 pk;
            pk.x = (unsigned)f2bf(dn * a0) | ((unsigned)f2bf(dn * a1) << 16);
            pk.y = (unsigned)f2bf(dn * a2) | ((unsigned)f2bf(dn * a3) << 16);
            *reinterpret_cast<uint2*>(&ynext[(size_t)n * 32 + m2]) = pk;
        }
    }
}

// ================= launch =================

extern "C" void kernel_launch(void* const* d_in, const int* in_sizes, int n_in,
                              void* d_out, int out_size, void* d_ws, size_t ws_size,
                              hipStream_t stream) {
    const int*   edge       = (const int*)d_in[0];
    const float* user_feat  = (const float*)d_in[1];
    const int*   cidx       = (const int*)d_in[2];
    const int*   sidx       = (const int*)d_in[3];
    const float* item_feat  = (const float*)d_in[4];
    const float* user_emb_w = (const float*)d_in[5];
    const float* item_emb_w = (const float*)d_in[6];
    const float* uWn        = (const float*)d_in[7];
    const float* ubn        = (const float*)d_in[8];
    const float* uWv        = (const float*)d_in[9];
    const float* ubv        = (const float*)d_in[10];
    const float* color_w    = (const float*)d_in[11];
    const float* size_w     = (const float*)d_in[12];
    const float* iWn        = (const float*)d_in[13];
    const float* ibn        = (const float*)d_in[14];
    const float* iWv        = (const float*)d_in[15];
    const float* ibv        = (const float*)d_in[16];

    const int E = in_sizes[0] / 2;
    const int U = in_sizes[5] / EMB;
    const int I = in_sizes[6] / EMB;
    const int N = U + I;
    const int NB = (N + 511) >> 9;     // 293 buckets

    const int* row = edge;
    const int* col = edge + E;

    float* total = (float*)d_out;      // running sum x + a1 + a2 + a3

    // workspace layout (u32 units)
    unsigned short* yA      = (unsigned short*)d_ws;          // [(N+1)*64] bf16
    unsigned short* yB      = yA + (size_t)(N + 1) * EMB;     // [(N+1)*64] bf16
    unsigned*       bucketbuf = (unsigned*)yB;                // [NB*BCAP] aliases yB
                                                              // (dummy row at word
                                                              // N*32=4.8M > 2.4M cap
                                                              // -> no overlap)
    unsigned*       srcidx  = (unsigned*)(yB + (size_t)(N + 1) * EMB);  // [NB*BSTRIDE]
    uint4*          meta    = (uint4*)(srcidx + (size_t)NB * BSTRIDE);  // [N]
    float*          dis     = (float*)(meta + N);             // [N]
    unsigned*       bcursor = (unsigned*)(dis + N);           // [NB]
    unsigned*       clsCnt  = bcursor + NB;                   // [64]
    unsigned*       clsCur  = clsCnt + 64;                    // [64]
    unsigned*       clsBase = clsCur + 64;                    // [64]
    unsigned*       order   = clsBase + 64;                   // [N]

    const int TB = 256;

    // 1. init (bcursor + class counters + phantom rows), then CSR build
    init_kernel<<<(NB + 128 + TB - 1) / TB, TB, 0, stream>>>(
        bcursor, NB + 128,
        (unsigned*)(yA + (size_t)N * EMB), (unsigned*)(yB + (size_t)N * EMB));
    const int gP = (E + CHUNK - 1) / CHUNK;
    partition_kernel<<<gP, TB, 0, stream>>>(row, col, bcursor, bucketbuf, E, NB);
    bucket_csr_kernel<<<NB, TB, 0, stream>>>(bcursor, bucketbuf, meta, dis,
                                             srcidx, clsCnt, N, NB);
    // degree-class scheduling order
    cls_scan_kernel<<<1, 64, 0, stream>>>(clsCnt, clsBase);
    order_fill_kernel<<<(N + TB - 1) / TB, TB, 0, stream>>>(meta, clsBase,
                                                            clsCur, order, N);

    // 2. fuse features: total = x, yA = bf16(dis*x)
    {
        int gU = (int)(((long)U * EMB + TB - 1) / TB);
        fuse_users_kernel<<<gU, TB, 0, stream>>>(user_feat, cidx, sidx, user_emb_w,
                                                 uWn, ubn, uWv, ubv, color_w, size_w,
                                                 dis, total, yA, U);
        int gI = (int)(((long)I * EMB + TB - 1) / TB);
        fuse_items_kernel<<<gI, TB, 0, stream>>>(item_feat, item_emb_w,
                                                 iWn, ibn, iWv, ibv,
                                                 dis, total, yA, I, U);
    }

    // 3. three propagation layers (gather form), total-accumulate fused
    const int gG = (N + 3) / 4;   // 4 degree-matched waves per block
    gather_propagate_kernel<<<gG, TB, 0, stream>>>(order, meta,
                                                   (const unsigned*)yA, srcidx,
                                                   (unsigned*)yB, (float4*)total,
                                                   1.0f, N, 1);
    gather_propagate_kernel<<<gG, TB, 0, stream>>>(order, meta,
                                                   (const unsigned*)yB, srcidx,
                                                   (unsigned*)yA, (float4*)total,
                                                   1.0f, N, 1);
    gather_propagate_kernel<<<gG, TB, 0, stream>>>(order, meta,
                                                   (const unsigned*)yA, srcidx,
                                                   (unsigned*)yB, (float4*)total,
                                                   0.25f, N, 0);

    (void)n_in; (void)out_size; (void)ws_size;
}

// Round 13
// 279.721 us; speedup vs baseline: 1.8049x; 1.0949x over previous
//
#include <hip/hip_runtime.h>

#define EMB 64
#define NBMAX 512      // max buckets (NB = ceil(N/512) = 293 for N=150000)
#define BCAP 8192      // bucket edge capacity (mean 6827, +16 sigma)
#define BSTRIDE 12288  // padded bucket region: BCAP + 512 nodes * 8 pad slots
#define CHUNK 4096     // edges per partition WG (489 blocks -> ~2/CU TLP)

// ---------------- bf16 helpers ----------------

__device__ __forceinline__ unsigned short f2bf(float f) {   // round-to-nearest-even
    union { float f; unsigned u; } c; c.f = f;
    unsigned r = c.u + 0x7fffu + ((c.u >> 16) & 1u);
    return (unsigned short)(r >> 16);
}
__device__ __forceinline__ float bflo(unsigned u) {         // low bf16 -> f32
    union { unsigned u; float f; } c; c.u = u << 16; return c.f;
}
__device__ __forceinline__ float bfhi(unsigned u) {         // high bf16 -> f32
    union { unsigned u; float f; } c; c.u = u & 0xffff0000u; return c.f;
}

// ================= init: zero bcursor/cls + phantom rows =================

__global__ void init_kernel(unsigned* __restrict__ p, int nz,
                            unsigned* __restrict__ dummyA,
                            unsigned* __restrict__ dummyB) {
    int i = blockIdx.x * blockDim.x + threadIdx.x;
    if (i < nz) p[i] = 0u;
    if (blockIdx.x == 0) {
        int t = threadIdx.x;
        if (t < 32) dummyA[t] = 0u;
        else if (t < 64) dummyB[t - 32] = 0u;
    }
}

// ================= feature fusion =================
// writes plain x into total (=d_out) and dis-premultiplied bf16 y into y0

__global__ void fuse_users_kernel(const float* __restrict__ feat,       // [U,15]
                                  const int* __restrict__ cidx,
                                  const int* __restrict__ sidx,
                                  const float* __restrict__ emb_w,      // [U,64]
                                  const float* __restrict__ Wn,         // [64,12]
                                  const float* __restrict__ bn,
                                  const float* __restrict__ Wv,         // [64,3]
                                  const float* __restrict__ bv,
                                  const float* __restrict__ color_w,    // [22,64]
                                  const float* __restrict__ size_w,     // [18,64]
                                  const float* __restrict__ dis,        // [N]
                                  float* __restrict__ total,            // [N,64]
                                  unsigned short* __restrict__ y0,      // [(N+1),64] bf16
                                  int U) {
    int t = blockIdx.x * blockDim.x + threadIdx.x;
    int u = t >> 6, d = t & 63;
    if (u >= U) return;
    const float* f = feat + (size_t)u * 15;
    float acc = emb_w[(size_t)u * EMB + d] + bn[d] + bv[d];
#pragma unroll
    for (int k = 0; k < 12; ++k) acc = fmaf(f[k], Wn[d * 12 + k], acc);
#pragma unroll
    for (int k = 0; k < 3; ++k) acc = fmaf(f[12 + k], Wv[d * 3 + k], acc);
    acc += color_w[(size_t)cidx[u] * EMB + d];
    acc += size_w[(size_t)sidx[u] * EMB + d];
    size_t o = (size_t)u * EMB + d;
    total[o] = acc;
    y0[o] = f2bf(acc * dis[u]);
}

__global__ void fuse_items_kernel(const float* __restrict__ feat,       // [I,17]
                                  const float* __restrict__ emb_w,      // [I,64]
                                  const float* __restrict__ Wn,         // [64,5]
                                  const float* __restrict__ bn,
                                  const float* __restrict__ Wv,         // [64,12]
                                  const float* __restrict__ bv,
                                  const float* __restrict__ dis,        // [N]
                                  float* __restrict__ total,
                                  unsigned short* __restrict__ y0,
                                  int I, int U) {
    int t = blockIdx.x * blockDim.x + threadIdx.x;
    int i = t >> 6, d = t & 63;
    if (i >= I) return;
    const float* f = feat + (size_t)i * 17;
    float acc = emb_w[(size_t)i * EMB + d] + bn[d] + bv[d];
#pragma unroll
    for (int k = 0; k < 5; ++k) acc = fmaf(f[k], Wn[d * 5 + k], acc);
#pragma unroll
    for (int k = 0; k < 12; ++k) acc = fmaf(f[5 + k], Wv[d * 12 + k], acc);
    int n = U + i;
    size_t o = (size_t)n * EMB + d;
    total[o] = acc;
    y0[o] = f2bf(acc * dis[n]);
}

// ================= bucketed CSR build =================
// pass 1: partition edges into NB col-range buckets (packed row<<9 | col&511)

__global__ __launch_bounds__(256) void partition_kernel(
        const int* __restrict__ row, const int* __restrict__ col,
        unsigned* __restrict__ bcursor, unsigned* __restrict__ bucketbuf,
        int E, int NB) {
    __shared__ unsigned h[NBMAX];
    __shared__ unsigned wbase[NBMAX];
    const int t = threadIdx.x;
    const long chunk = (long)blockIdx.x * CHUNK;

    for (int i = t; i < NB; i += 256) h[i] = 0u;
    __syncthreads();
    for (int it = 0; it < CHUNK / 256; ++it) {
        long e = chunk + (long)it * 256 + t;
        if (e < E) atomicAdd(&h[((unsigned)col[e]) >> 9], 1u);
    }
    __syncthreads();
    for (int i = t; i < NB; i += 256) {
        unsigned c = h[i];
        wbase[i] = c ? atomicAdd(&bcursor[i], c) : 0u;
    }
    __syncthreads();
    for (int i = t; i < NB; i += 256) h[i] = 0u;
    __syncthreads();
    for (int it = 0; it < CHUNK / 256; ++it) {
        long e = chunk + (long)it * 256 + t;
        if (e < E) {
            unsigned c = (unsigned)col[e];
            unsigned b = c >> 9;
            unsigned lpos = atomicAdd(&h[b], 1u);
            unsigned pos = wbase[b] + lpos;
            if (pos < BCAP)
                bucketbuf[(size_t)b * BCAP + pos] = (((unsigned)row[e]) << 9) | (c & 511u);
        }
    }
}

// pass 2: one WG per bucket -> meta (pad-8 lists), dis, srcidx (pre-shifted
// word offsets r*32 + phantom pads), degree-class counts

__global__ __launch_bounds__(256) void bucket_csr_kernel(
        const unsigned* __restrict__ bcursor,   // final per-bucket counts
        const unsigned* __restrict__ bucketbuf,
        uint4* __restrict__ meta,               // [N] {beg,end,dis_bits,0}
        float* __restrict__ dis, unsigned* __restrict__ srcidx,
        unsigned* __restrict__ clsCnt,          // [64] global degree-class counts
        int N, int NB) {
    const int b = blockIdx.x;
    const int t = threadIdx.x;
    __shared__ unsigned hist[512];
    __shared__ unsigned ps[256];
    __shared__ unsigned cls[64];

    const unsigned base = (unsigned)b * BSTRIDE;
    unsigned cntb = bcursor[b];
    if (cntb > BCAP) cntb = BCAP;

    hist[2 * t] = 0u; hist[2 * t + 1] = 0u;
    if (t < 64) cls[t] = 0u;
    __syncthreads();
    const unsigned* buf = bucketbuf + (size_t)b * BCAP;
    for (unsigned j = t; j < cntb; j += 256) atomicAdd(&hist[buf[j] & 511u], 1u);
    __syncthreads();

    unsigned h0 = hist[2 * t], h1 = hist[2 * t + 1];
    unsigned c0p = (h0 + 7u) & ~7u, c1p = (h1 + 7u) & ~7u;   // pad to multiple of 8
    ps[t] = c0p + c1p;
    __syncthreads();
    for (int off = 1; off < 256; off <<= 1) {
        unsigned y = (t >= off) ? ps[t - off] : 0u;
        __syncthreads();
        ps[t] += y;
        __syncthreads();
    }
    unsigned pexcl = ps[t] - (c0p + c1p);
    unsigned beg0 = base + pexcl, beg1 = beg0 + c0p;

    int n0 = (b << 9) + 2 * t, n1 = n0 + 1;
    if (n0 < N) {
        float dv = h0 ? rsqrtf((float)h0) : 0.f;
        meta[n0] = make_uint4(beg0, beg0 + c0p, __float_as_uint(dv), 0u);
        dis[n0] = dv;
        atomicAdd(&cls[min(c0p >> 3, 63u)], 1u);
        for (unsigned k = h0; k < c0p; ++k) srcidx[beg0 + k] = ((unsigned)N) << 5;
    }
    if (n1 < N) {
        float dv = h1 ? rsqrtf((float)h1) : 0.f;
        meta[n1] = make_uint4(beg1, beg1 + c1p, __float_as_uint(dv), 0u);
        dis[n1] = dv;
        atomicAdd(&cls[min(c1p >> 3, 63u)], 1u);
        for (unsigned k = h1; k < c1p; ++k) srcidx[beg1 + k] = ((unsigned)N) << 5;
    }
    __syncthreads();

    if (t < 64 && cls[t]) atomicAdd(&clsCnt[t], cls[t]);
    // repurpose hist as scatter cursors
    hist[2 * t] = beg0; hist[2 * t + 1] = beg1;
    __syncthreads();
    for (unsigned j = t; j < cntb; j += 256) {
        unsigned p = buf[j];
        unsigned pos = atomicAdd(&hist[p & 511u], 1u);
        srcidx[pos] = (p >> 9) << 5;   // u32 word offset of source row
    }
}

// exclusive scan of the 64 class counts -> clsBase

__global__ void cls_scan_kernel(const unsigned* __restrict__ clsCnt,
                                unsigned* __restrict__ clsBase) {
    __shared__ unsigned sh[64];
    int t = threadIdx.x;
    if (t < 64) sh[t] = clsCnt[t];
    __syncthreads();
    if (t == 0) {
        unsigned run = 0;
        for (int i = 0; i < 64; ++i) { unsigned v = sh[i]; sh[i] = run; run += v; }
    }
    __syncthreads();
    if (t < 64) clsBase[t] = sh[t];
}

// counting-sort node ids by degree class into order[] (LDS-aggregated)

__global__ __launch_bounds__(256) void order_fill_kernel(
        const uint4* __restrict__ meta,
        const unsigned* __restrict__ clsBase, unsigned* __restrict__ clsCur,
        unsigned* __restrict__ order, int N) {
    __shared__ unsigned h[64], wb[64];
    int t = threadIdx.x;
    int n = blockIdx.x * 256 + t;
    if (t < 64) h[t] = 0u;
    __syncthreads();
    unsigned c = 0, lpos = 0;
    bool valid = n < N;
    if (valid) {
        uint4 md = meta[n];
        c = min((md.y - md.x) >> 3, 63u);
        lpos = atomicAdd(&h[c], 1u);
    }
    __syncthreads();
    if (t < 64) wb[t] = h[t] ? atomicAdd(&clsCur[t], h[t]) : 0u;
    __syncthreads();
    if (valid) order[clsBase[c] + wb[c] + lpos] = (unsigned)n;
}

// ================= propagation =================
// TWO nodes per wave: lane = (h, q, m). Half h (lanes 0-31 / 32-63) owns node
// order[slot_h] (degree-sorted -> equal trip counts). Per 8-edge step per
// node the wave issues 1 uint4 idx load (4 distinct addresses, (h,q) groups)
// + 4 uint2 row loads (4 distinct rows each) -> 16 edges / 5 VMEM with TWO
// independent dependency chains. Lists are pad-8 -> no tail code at all.
// Epilogue: one shfl_xor(16) per acc combines q-groups within each half.

__global__ __launch_bounds__(256) void gather_propagate_kernel(
        const unsigned* __restrict__ order, const uint4* __restrict__ meta,
        const unsigned* __restrict__ src,   // [(N+1)*32]
        const unsigned* __restrict__ srcidx,
        unsigned* __restrict__ ynext,      // [(N+1)*32]
        float4* __restrict__ total4,       // [N*16]
        float scale, int N, int store) {
    int lane = threadIdx.x & 63;
    int slot = blockIdx.x * 8 + ((threadIdx.x >> 6) << 1) + (lane >> 5);
    bool active = slot < N;
    int n = active ? (int)order[slot] : 0;
    uint4 md = active ? meta[n] : make_uint4(0u, 0u, 0u, 0u);
    unsigned beg = md.x, endp = md.y;
    float dn = __uint_as_float(md.z);
    unsigned q = (unsigned)((lane >> 4) & 1);
    unsigned m2 = (unsigned)(lane & 15) * 2u;
    float s0 = 0.f, s1 = 0.f, s2 = 0.f, s3 = 0.f;
    for (unsigned j = beg; j < endp; j += 8) {
        uint4 iv = *reinterpret_cast<const uint4*>(&srcidx[j + 4u * q]);
        uint2 ua = *reinterpret_cast<const uint2*>(&src[iv.x + m2]);
        uint2 ub = *reinterpret_cast<const uint2*>(&src[iv.y + m2]);
        uint2 uc = *reinterpret_cast<const uint2*>(&src[iv.z + m2]);
        uint2 ud = *reinterpret_cast<const uint2*>(&src[iv.w + m2]);
        s0 += (bflo(ua.x) + bflo(ub.x)) + (bflo(uc.x) + bflo(ud.x));
        s1 += (bfhi(ua.x) + bfhi(ub.x)) + (bfhi(uc.x) + bfhi(ud.x));
        s2 += (bflo(ua.y) + bflo(ub.y)) + (bflo(uc.y) + bflo(ud.y));
        s3 += (bfhi(ua.y) + bfhi(ub.y)) + (bfhi(uc.y) + bfhi(ud.y));
    }
    // combine the two q-groups within each half (xor 16 stays inside the half)
    s0 += __shfl_xor(s0, 16);
    s1 += __shfl_xor(s1, 16);
    s2 += __shfl_xor(s2, 16);
    s3 += __shfl_xor(s3, 16);
    if (active && (lane & 31) < 16) {
        float a0 = dn * s0, a1 = dn * s1, a2 = dn * s2, a3 = dn * s3;
        size_t o4 = (size_t)n * 16 + (m2 >> 1);
        float4 tv = total4[o4];
        total4[o4] = make_float4((tv.x + a0) * scale, (tv.y + a1) * scale,
                                 (tv.z + a2) * scale, (tv.w + a3) * scale);
        if (store) {
            uint2 pk;
            pk.x = (unsigned)f2bf(dn * a0) | ((unsigned)f2bf(dn * a1) << 16);
            pk.y = (unsigned)f2bf(dn * a2) | ((unsigned)f2bf(dn * a3) << 16);
            *reinterpret_cast<uint2*>(&ynext[(size_t)n * 32 + m2]) = pk;
        }
    }
}

// ================= launch =================

extern "C" void kernel_launch(void* const* d_in, const int* in_sizes, int n_in,
                              void* d_out, int out_size, void* d_ws, size_t ws_size,
                              hipStream_t stream) {
    const int*   edge       = (const int*)d_in[0];
    const float* user_feat  = (const float*)d_in[1];
    const int*   cidx       = (const int*)d_in[2];
    const int*   sidx       = (const int*)d_in[3];
    const float* item_feat  = (const float*)d_in[4];
    const float* user_emb_w = (const float*)d_in[5];
    const float* item_emb_w = (const float*)d_in[6];
    const float* uWn        = (const float*)d_in[7];
    const float* ubn        = (const float*)d_in[8];
    const float* uWv        = (const float*)d_in[9];
    const float* ubv        = (const float*)d_in[10];
    const float* color_w    = (const float*)d_in[11];
    const float* size_w     = (const float*)d_in[12];
    const float* iWn        = (const float*)d_in[13];
    const float* ibn        = (const float*)d_in[14];
    const float* iWv        = (const float*)d_in[15];
    const float* ibv        = (const float*)d_in[16];

    const int E = in_sizes[0] / 2;
    const int U = in_sizes[5] / EMB;
    const int I = in_sizes[6] / EMB;
    const int N = U + I;
    const int NB = (N + 511) >> 9;     // 293 buckets

    const int* row = edge;
    const int* col = edge + E;

    float* total = (float*)d_out;      // running sum x + a1 + a2 + a3

    // workspace layout (u32 units)
    unsigned short* yA      = (unsigned short*)d_ws;          // [(N+1)*64] bf16
    unsigned short* yB      = yA + (size_t)(N + 1) * EMB;     // [(N+1),64] bf16
    unsigned*       bucketbuf = (unsigned*)yB;                // [NB*BCAP] aliases yB
                                                              // (dummy row at word
                                                              // N*32=4.8M > 2.4M cap
                                                              // -> no overlap)
    unsigned*       srcidx  = (unsigned*)(yB + (size_t)(N + 1) * EMB);  // [NB*BSTRIDE]
    uint4*          meta    = (uint4*)(srcidx + (size_t)NB * BSTRIDE);  // [N]
    float*          dis     = (float*)(meta + N);             // [N]
    unsigned*       bcursor = (unsigned*)(dis + N);           // [NB]
    unsigned*       clsCnt  = bcursor + NB;                   // [64]
    unsigned*       clsCur  = clsCnt + 64;                    // [64]
    unsigned*       clsBase = clsCur + 64;                    // [64]
    unsigned*       order   = clsBase + 64;                   // [N]

    const int TB = 256;

    // 1. init (bcursor + class counters + phantom rows), then CSR build
    init_kernel<<<(NB + 128 + TB - 1) / TB, TB, 0, stream>>>(
        bcursor, NB + 128,
        (unsigned*)(yA + (size_t)N * EMB), (unsigned*)(yB + (size_t)N * EMB));
    const int gP = (E + CHUNK - 1) / CHUNK;
    partition_kernel<<<gP, TB, 0, stream>>>(row, col, bcursor, bucketbuf, E, NB);
    bucket_csr_kernel<<<NB, TB, 0, stream>>>(bcursor, bucketbuf, meta, dis,
                                             srcidx, clsCnt, N, NB);
    // degree-class scheduling order
    cls_scan_kernel<<<1, 64, 0, stream>>>(clsCnt, clsBase);
    order_fill_kernel<<<(N + TB - 1) / TB, TB, 0, stream>>>(meta, clsBase,
                                                            clsCur, order, N);

    // 2. fuse features: total = x, yA = bf16(dis*x)
    {
        int gU = (int)(((long)U * EMB + TB - 1) / TB);
        fuse_users_kernel<<<gU, TB, 0, stream>>>(user_feat, cidx, sidx, user_emb_w,
                                                 uWn, ubn, uWv, ubv, color_w, size_w,
                                                 dis, total, yA, U);
        int gI = (int)(((long)I * EMB + TB - 1) / TB);
        fuse_items_kernel<<<gI, TB, 0, stream>>>(item_feat, item_emb_w,
                                                 iWn, ibn, iWv, ibv,
                                                 dis, total, yA, I, U);
    }

    // 3. three propagation layers (gather form), total-accumulate fused
    const int gG = (N + 7) / 8;   // 8 degree-matched nodes per block (2/wave)
    gather_propagate_kernel<<<gG, TB, 0, stream>>>(order, meta,
                                                   (const unsigned*)yA, srcidx,
                                                   (unsigned*)yB, (float4*)total,
                                                   1.0f, N, 1);
    gather_propagate_kernel<<<gG, TB, 0, stream>>>(order, meta,
                                                   (const unsigned*)yB, srcidx,
                                                   (unsigned*)yA, (float4*)total,
                                                   1.0f, N, 1);
    gather_propagate_kernel<<<gG, TB, 0, stream>>>(order, meta,
                                                   (const unsigned*)yA, srcidx,
                                                   (unsigned*)yB, (float4*)total,
                                                   0.25f, N, 0);

    (void)n_in; (void)out_size; (void)ws_size;
}

// Round 14
// 259.244 us; speedup vs baseline: 1.9475x; 1.0790x over previous
//
#include <hip/hip_runtime.h>

#define EMB 64
#define NBMAX 512      // max buckets (NB = ceil(N/512) = 293 for N=150000)
#define BCAP 8192      // bucket edge capacity (mean 6827, +16 sigma)
#define BSTRIDE 12288  // padded bucket region: BCAP + 512 nodes * 8 pad slots
#define CHUNK 4096     // edges per partition WG

// ---------------- bf16 helpers ----------------

__device__ __forceinline__ unsigned short f2bf(float f) {   // round-to-nearest-even
    union { float f; unsigned u; } c; c.f = f;
    unsigned r = c.u + 0x7fffu + ((c.u >> 16) & 1u);
    return (unsigned short)(r >> 16);
}
__device__ __forceinline__ float bflo(unsigned u) {         // low bf16 -> f32
    union { unsigned u; float f; } c; c.u = u << 16; return c.f;
}
__device__ __forceinline__ float bfhi(unsigned u) {         // high bf16 -> f32
    union { unsigned u; float f; } c; c.u = u & 0xffff0000u; return c.f;
}
__device__ __forceinline__ unsigned pack2(float a, float b) {
    return (unsigned)f2bf(a) | ((unsigned)f2bf(b) << 16);
}

// ================= init: zero bcursor/cls + phantom rows =================

__global__ void init_kernel(unsigned* __restrict__ p, int nz,
                            unsigned* __restrict__ dummyA,
                            unsigned* __restrict__ dummyB) {
    int i = blockIdx.x * blockDim.x + threadIdx.x;
    if (i < nz) p[i] = 0u;
    if (blockIdx.x == 0) {
        int t = threadIdx.x;
        if (t < 32) dummyA[t] = 0u;
        else if (t < 64) dummyB[t - 32] = 0u;
    }
}

// ================= feature fusion =================
// writes bf16 x into totB and dis-premultiplied bf16 y into y0

__global__ void fuse_users_kernel(const float* __restrict__ feat,       // [U,15]
                                  const int* __restrict__ cidx,
                                  const int* __restrict__ sidx,
                                  const float* __restrict__ emb_w,      // [U,64]
                                  const float* __restrict__ Wn,         // [64,12]
                                  const float* __restrict__ bn,
                                  const float* __restrict__ Wv,         // [64,3]
                                  const float* __restrict__ bv,
                                  const float* __restrict__ color_w,    // [22,64]
                                  const float* __restrict__ size_w,     // [18,64]
                                  const float* __restrict__ dis,        // [N]
                                  unsigned short* __restrict__ totB,    // [N,64] bf16
                                  unsigned short* __restrict__ y0,      // [(N+1),64] bf16
                                  int U) {
    int t = blockIdx.x * blockDim.x + threadIdx.x;
    int u = t >> 6, d = t & 63;
    if (u >= U) return;
    const float* f = feat + (size_t)u * 15;
    float acc = emb_w[(size_t)u * EMB + d] + bn[d] + bv[d];
#pragma unroll
    for (int k = 0; k < 12; ++k) acc = fmaf(f[k], Wn[d * 12 + k], acc);
#pragma unroll
    for (int k = 0; k < 3; ++k) acc = fmaf(f[12 + k], Wv[d * 3 + k], acc);
    acc += color_w[(size_t)cidx[u] * EMB + d];
    acc += size_w[(size_t)sidx[u] * EMB + d];
    size_t o = (size_t)u * EMB + d;
    totB[o] = f2bf(acc);
    y0[o] = f2bf(acc * dis[u]);
}

__global__ void fuse_items_kernel(const float* __restrict__ feat,       // [I,17]
                                  const float* __restrict__ emb_w,      // [I,64]
                                  const float* __restrict__ Wn,         // [64,5]
                                  const float* __restrict__ bn,
                                  const float* __restrict__ Wv,         // [64,12]
                                  const float* __restrict__ bv,
                                  const float* __restrict__ dis,        // [N]
                                  unsigned short* __restrict__ totB,
                                  unsigned short* __restrict__ y0,
                                  int I, int U) {
    int t = blockIdx.x * blockDim.x + threadIdx.x;
    int i = t >> 6, d = t & 63;
    if (i >= I) return;
    const float* f = feat + (size_t)i * 17;
    float acc = emb_w[(size_t)i * EMB + d] + bn[d] + bv[d];
#pragma unroll
    for (int k = 0; k < 5; ++k) acc = fmaf(f[k], Wn[d * 5 + k], acc);
#pragma unroll
    for (int k = 0; k < 12; ++k) acc = fmaf(f[5 + k], Wv[d * 12 + k], acc);
    int n = U + i;
    size_t o = (size_t)n * EMB + d;
    totB[o] = f2bf(acc);
    y0[o] = f2bf(acc * dis[n]);
}

// ================= bucketed CSR build =================
// pass 1: partition edges into NB col-range buckets (packed row<<9 | col&511)

__global__ __launch_bounds__(512) void partition_kernel(
        const int* __restrict__ row, const int* __restrict__ col,
        unsigned* __restrict__ bcursor, unsigned* __restrict__ bucketbuf,
        int E, int NB) {
    __shared__ unsigned h[NBMAX];
    __shared__ unsigned wbase[NBMAX];
    const int t = threadIdx.x;
    const long chunk = (long)blockIdx.x * CHUNK;

    for (int i = t; i < NB; i += 512) h[i] = 0u;
    __syncthreads();
    for (int it = 0; it < CHUNK / 512; ++it) {
        long e = chunk + (long)it * 512 + t;
        if (e < E) atomicAdd(&h[((unsigned)col[e]) >> 9], 1u);
    }
    __syncthreads();
    for (int i = t; i < NB; i += 512) {
        unsigned c = h[i];
        wbase[i] = c ? atomicAdd(&bcursor[i], c) : 0u;
    }
    __syncthreads();
    for (int i = t; i < NB; i += 512) h[i] = 0u;
    __syncthreads();
    for (int it = 0; it < CHUNK / 512; ++it) {
        long e = chunk + (long)it * 512 + t;
        if (e < E) {
            unsigned c = (unsigned)col[e];
            unsigned b = c >> 9;
            unsigned lpos = atomicAdd(&h[b], 1u);
            unsigned pos = wbase[b] + lpos;
            if (pos < BCAP)
                bucketbuf[(size_t)b * BCAP + pos] = (((unsigned)row[e]) << 9) | (c & 511u);
        }
    }
}

// pass 2: one 512-thread WG per bucket (1 node/thread) -> meta (pad-8 lists),
// dis, srcidx (pre-shifted word offsets r*32 + phantom pads), class counts

__global__ __launch_bounds__(512) void bucket_csr_kernel(
        const unsigned* __restrict__ bcursor,   // final per-bucket counts
        const unsigned* __restrict__ bucketbuf,
        uint4* __restrict__ meta,               // [N] {beg,end,dis_bits,0}
        float* __restrict__ dis, unsigned* __restrict__ srcidx,
        unsigned* __restrict__ clsCnt,          // [64] global degree-class counts
        int N, int NB) {
    const int b = blockIdx.x;
    const int t = threadIdx.x;
    __shared__ unsigned hist[512];
    __shared__ unsigned ps[512];
    __shared__ unsigned cls[64];

    const unsigned base = (unsigned)b * BSTRIDE;
    unsigned cntb = bcursor[b];
    if (cntb > BCAP) cntb = BCAP;

    hist[t] = 0u;
    if (t < 64) cls[t] = 0u;
    __syncthreads();
    const unsigned* buf = bucketbuf + (size_t)b * BCAP;
    for (unsigned j = t; j < cntb; j += 512) atomicAdd(&hist[buf[j] & 511u], 1u);
    __syncthreads();

    unsigned h0 = hist[t];
    unsigned c0p = (h0 + 7u) & ~7u;    // pad to multiple of 8
    ps[t] = c0p;
    __syncthreads();
    for (int off = 1; off < 512; off <<= 1) {
        unsigned y = (t >= off) ? ps[t - off] : 0u;
        __syncthreads();
        ps[t] += y;
        __syncthreads();
    }
    unsigned beg0 = base + ps[t] - c0p;

    int n0 = (b << 9) + t;
    if (n0 < N) {
        float dv = h0 ? rsqrtf((float)h0) : 0.f;
        meta[n0] = make_uint4(beg0, beg0 + c0p, __float_as_uint(dv), 0u);
        dis[n0] = dv;
        atomicAdd(&cls[min(c0p >> 3, 63u)], 1u);
        for (unsigned k = h0; k < c0p; ++k) srcidx[beg0 + k] = ((unsigned)N) << 5;
    }
    __syncthreads();

    if (t < 64 && cls[t]) atomicAdd(&clsCnt[t], cls[t]);
    // repurpose hist as scatter cursors
    hist[t] = beg0;
    __syncthreads();
    for (unsigned j = t; j < cntb; j += 512) {
        unsigned p = buf[j];
        unsigned pos = atomicAdd(&hist[p & 511u], 1u);
        srcidx[pos] = (p >> 9) << 5;   // u32 word offset of source row
    }
}

// exclusive scan of the 64 class counts -> clsBase

__global__ void cls_scan_kernel(const unsigned* __restrict__ clsCnt,
                                unsigned* __restrict__ clsBase) {
    __shared__ unsigned sh[64];
    int t = threadIdx.x;
    if (t < 64) sh[t] = clsCnt[t];
    __syncthreads();
    if (t == 0) {
        unsigned run = 0;
        for (int i = 0; i < 64; ++i) { unsigned v = sh[i]; sh[i] = run; run += v; }
    }
    __syncthreads();
    if (t < 64) clsBase[t] = sh[t];
}

// counting-sort node ids by degree class into order[] (LDS-aggregated)

__global__ __launch_bounds__(256) void order_fill_kernel(
        const uint4* __restrict__ meta,
        const unsigned* __restrict__ clsBase, unsigned* __restrict__ clsCur,
        unsigned* __restrict__ order, int N) {
    __shared__ unsigned h[64], wb[64];
    int t = threadIdx.x;
    int n = blockIdx.x * 256 + t;
    if (t < 64) h[t] = 0u;
    __syncthreads();
    unsigned c = 0, lpos = 0;
    bool valid = n < N;
    if (valid) {
        uint4 md = meta[n];
        c = min((md.y - md.x) >> 3, 63u);
        lpos = atomicAdd(&h[c], 1u);
    }
    __syncthreads();
    if (t < 64) wb[t] = h[t] ? atomicAdd(&clsCur[t], h[t]) : 0u;
    __syncthreads();
    if (valid) order[clsBase[c] + wb[c] + lpos] = (unsigned)n;
}

// ================= propagation =================
// TWO nodes per wave (degree-sorted), 16-edge unrolled main loop with two
// independent accumulator banks + one 8-edge tail (lists pad-8). Running
// total is bf16 (totB) -> RMW traffic halved; final kernel converts to f32.

__global__ __launch_bounds__(256) void gather_propagate_kernel(
        const unsigned* __restrict__ order, const uint4* __restrict__ meta,
        const unsigned* __restrict__ src,   // [(N+1)*32]
        const unsigned* __restrict__ srcidx,
        unsigned* __restrict__ ynext,       // [(N+1)*32]
        unsigned* __restrict__ totB,        // [N*32] bf16x2 RMW
        int N, int store) {
    int lane = threadIdx.x & 63;
    int slot = blockIdx.x * 8 + ((threadIdx.x >> 6) << 1) + (lane >> 5);
    bool active = slot < N;
    int n = active ? (int)order[slot] : 0;
    uint4 md = active ? meta[n] : make_uint4(0u, 0u, 0u, 0u);
    unsigned beg = md.x, endp = md.y;
    float dn = __uint_as_float(md.z);
    unsigned q = (unsigned)((lane >> 4) & 1);
    unsigned m2 = (unsigned)(lane & 15) * 2u;
    float s0 = 0.f, s1 = 0.f, s2 = 0.f, s3 = 0.f;
    float t0 = 0.f, t1 = 0.f, t2 = 0.f, t3 = 0.f;
    unsigned j = beg;
    for (; j + 16 <= endp; j += 16) {   // 16 edges/node/iter, 2 chains
        uint4 iv0 = *reinterpret_cast<const uint4*>(&srcidx[j + 4u * q]);
        uint4 iv1 = *reinterpret_cast<const uint4*>(&srcidx[j + 8u + 4u * q]);
        uint2 ua = *reinterpret_cast<const uint2*>(&src[iv0.x + m2]);
        uint2 ub = *reinterpret_cast<const uint2*>(&src[iv0.y + m2]);
        uint2 uc = *reinterpret_cast<const uint2*>(&src[iv0.z + m2]);
        uint2 ud = *reinterpret_cast<const uint2*>(&src[iv0.w + m2]);
        uint2 ue = *reinterpret_cast<const uint2*>(&src[iv1.x + m2]);
        uint2 uf = *reinterpret_cast<const uint2*>(&src[iv1.y + m2]);
        uint2 ug = *reinterpret_cast<const uint2*>(&src[iv1.z + m2]);
        uint2 uh = *reinterpret_cast<const uint2*>(&src[iv1.w + m2]);
        s0 += (bflo(ua.x) + bflo(ub.x)) + (bflo(uc.x) + bflo(ud.x));
        s1 += (bfhi(ua.x) + bfhi(ub.x)) + (bfhi(uc.x) + bfhi(ud.x));
        s2 += (bflo(ua.y) + bflo(ub.y)) + (bflo(uc.y) + bflo(ud.y));
        s3 += (bfhi(ua.y) + bfhi(ub.y)) + (bfhi(uc.y) + bfhi(ud.y));
        t0 += (bflo(ue.x) + bflo(uf.x)) + (bflo(ug.x) + bflo(uh.x));
        t1 += (bfhi(ue.x) + bfhi(uf.x)) + (bfhi(ug.x) + bfhi(uh.x));
        t2 += (bflo(ue.y) + bflo(uf.y)) + (bflo(ug.y) + bflo(uh.y));
        t3 += (bfhi(ue.y) + bfhi(uf.y)) + (bfhi(ug.y) + bfhi(uh.y));
    }
    if (j < endp) {   // exactly one 8-edge tail (pad-8 lists)
        uint4 iv = *reinterpret_cast<const uint4*>(&srcidx[j + 4u * q]);
        uint2 ua = *reinterpret_cast<const uint2*>(&src[iv.x + m2]);
        uint2 ub = *reinterpret_cast<const uint2*>(&src[iv.y + m2]);
        uint2 uc = *reinterpret_cast<const uint2*>(&src[iv.z + m2]);
        uint2 ud = *reinterpret_cast<const uint2*>(&src[iv.w + m2]);
        s0 += (bflo(ua.x) + bflo(ub.x)) + (bflo(uc.x) + bflo(ud.x));
        s1 += (bfhi(ua.x) + bfhi(ub.x)) + (bfhi(uc.x) + bfhi(ud.x));
        s2 += (bflo(ua.y) + bflo(ub.y)) + (bflo(uc.y) + bflo(ud.y));
        s3 += (bfhi(ua.y) + bfhi(ub.y)) + (bfhi(uc.y) + bfhi(ud.y));
    }
    s0 += t0; s1 += t1; s2 += t2; s3 += t3;
    // combine the two q-groups within each half (xor 16 stays inside the half)
    s0 += __shfl_xor(s0, 16);
    s1 += __shfl_xor(s1, 16);
    s2 += __shfl_xor(s2, 16);
    s3 += __shfl_xor(s3, 16);
    if (active && (lane & 31) < 16) {
        float a0 = dn * s0, a1 = dn * s1, a2 = dn * s2, a3 = dn * s3;
        size_t o = (size_t)n * 32 + m2;
        uint2 tv = *reinterpret_cast<const uint2*>(&totB[o]);
        uint2 nv;
        nv.x = pack2(bflo(tv.x) + a0, bfhi(tv.x) + a1);
        nv.y = pack2(bflo(tv.y) + a2, bfhi(tv.y) + a3);
        *reinterpret_cast<uint2*>(&totB[o]) = nv;
        if (store) {
            uint2 pk;
            pk.x = pack2(dn * a0, dn * a1);
            pk.y = pack2(dn * a2, dn * a3);
            *reinterpret_cast<uint2*>(&ynext[(size_t)n * 32 + m2]) = pk;
        }
    }
}

// ================= finalize: out = f32(totB) / 4 =================

__global__ void finalize_kernel(const unsigned* __restrict__ totB,
                                float2* __restrict__ out2, long n32) {
    long t = (long)blockIdx.x * blockDim.x + threadIdx.x;
    if (t < n32) {
        unsigned u = totB[t];
        out2[t] = make_float2(bflo(u) * 0.25f, bfhi(u) * 0.25f);
    }
}

// ================= launch =================

extern "C" void kernel_launch(void* const* d_in, const int* in_sizes, int n_in,
                              void* d_out, int out_size, void* d_ws, size_t ws_size,
                              hipStream_t stream) {
    const int*   edge       = (const int*)d_in[0];
    const float* user_feat  = (const float*)d_in[1];
    const int*   cidx       = (const int*)d_in[2];
    const int*   sidx       = (const int*)d_in[3];
    const float* item_feat  = (const float*)d_in[4];
    const float* user_emb_w = (const float*)d_in[5];
    const float* item_emb_w = (const float*)d_in[6];
    const float* uWn        = (const float*)d_in[7];
    const float* ubn        = (const float*)d_in[8];
    const float* uWv        = (const float*)d_in[9];
    const float* ubv        = (const float*)d_in[10];
    const float* color_w    = (const float*)d_in[11];
    const float* size_w     = (const float*)d_in[12];
    const float* iWn        = (const float*)d_in[13];
    const float* ibn        = (const float*)d_in[14];
    const float* iWv        = (const float*)d_in[15];
    const float* ibv        = (const float*)d_in[16];

    const int E = in_sizes[0] / 2;
    const int U = in_sizes[5] / EMB;
    const int I = in_sizes[6] / EMB;
    const int N = U + I;
    const int NB = (N + 511) >> 9;     // 293 buckets

    const int* row = edge;
    const int* col = edge + E;

    // workspace layout (u32 units)
    unsigned short* yA      = (unsigned short*)d_ws;          // [(N+1)*64] bf16
    unsigned short* yB      = yA + (size_t)(N + 1) * EMB;     // [(N+1)*64] bf16
    unsigned*       bucketbuf = (unsigned*)yB;                // [NB*BCAP] aliases yB
                                                              // (dummy row at word
                                                              // N*32=4.8M > 2.4M cap
                                                              // -> no overlap)
    unsigned short* totB    = yB + (size_t)(N + 1) * EMB;     // [N*64] bf16 running sum
    unsigned*       srcidx  = (unsigned*)(totB + (size_t)N * EMB);      // [NB*BSTRIDE]
    uint4*          meta    = (uint4*)(srcidx + (size_t)NB * BSTRIDE);  // [N]
    float*          dis     = (float*)(meta + N);             // [N]
    unsigned*       bcursor = (unsigned*)(dis + N);           // [NB]
    unsigned*       clsCnt  = bcursor + NB;                   // [64]
    unsigned*       clsCur  = clsCnt + 64;                    // [64]
    unsigned*       clsBase = clsCur + 64;                    // [64]
    unsigned*       order   = clsBase + 64;                   // [N]

    const int TB = 256;

    // 1. init (bcursor + class counters + phantom rows), then CSR build
    init_kernel<<<(NB + 128 + TB - 1) / TB, TB, 0, stream>>>(
        bcursor, NB + 128,
        (unsigned*)(yA + (size_t)N * EMB), (unsigned*)(yB + (size_t)N * EMB));
    const int gP = (E + CHUNK - 1) / CHUNK;
    partition_kernel<<<gP, 512, 0, stream>>>(row, col, bcursor, bucketbuf, E, NB);
    bucket_csr_kernel<<<NB, 512, 0, stream>>>(bcursor, bucketbuf, meta, dis,
                                              srcidx, clsCnt, N, NB);
    // degree-class scheduling order
    cls_scan_kernel<<<1, 64, 0, stream>>>(clsCnt, clsBase);
    order_fill_kernel<<<(N + TB - 1) / TB, TB, 0, stream>>>(meta, clsBase,
                                                            clsCur, order, N);

    // 2. fuse features: totB = bf16(x), yA = bf16(dis*x)
    {
        int gU = (int)(((long)U * EMB + TB - 1) / TB);
        fuse_users_kernel<<<gU, TB, 0, stream>>>(user_feat, cidx, sidx, user_emb_w,
                                                 uWn, ubn, uWv, ubv, color_w, size_w,
                                                 dis, totB, yA, U);
        int gI = (int)(((long)I * EMB + TB - 1) / TB);
        fuse_items_kernel<<<gI, TB, 0, stream>>>(item_feat, item_emb_w,
                                                 iWn, ibn, iWv, ibv,
                                                 dis, totB, yA, I, U);
    }

    // 3. three propagation layers (gather form), totB-accumulate fused
    const int gG = (N + 7) / 8;   // 8 degree-matched nodes per block (2/wave)
    gather_propagate_kernel<<<gG, TB, 0, stream>>>(order, meta,
                                                   (const unsigned*)yA, srcidx,
                                                   (unsigned*)yB, (unsigned*)totB,
                                                   N, 1);
    gather_propagate_kernel<<<gG, TB, 0, stream>>>(order, meta,
                                                   (const unsigned*)yB, srcidx,
                                                   (unsigned*)yA, (unsigned*)totB,
                                                   N, 1);
    gather_propagate_kernel<<<gG, TB, 0, stream>>>(order, meta,
                                                   (const unsigned*)yA, srcidx,
                                                   (unsigned*)yB, (unsigned*)totB,
                                                   N, 0);

    // 4. finalize: d_out = f32(totB) * 0.25
    const long n32 = (long)N * 32;
    finalize_kernel<<<(int)((n32 + TB - 1) / TB), TB, 0, stream>>>(
        (const unsigned*)totB, (float2*)d_out, n32);

    (void)n_in; (void)out_size; (void)ws_size;
}

// Round 15
// 236.558 us; speedup vs baseline: 2.1342x; 1.0959x over previous
//
#include <hip/hip_runtime.h>

#define EMB 64
#define NBMAX 512      // max buckets (NB = ceil(N/512) = 293 for N=150000)
#define BCAP 8192      // bucket edge capacity (mean 6827, +16 sigma)
#define BSTRIDE 12288  // padded bucket region: BCAP + 512 nodes * 8 pad slots
#define CHUNK 4096     // edges per partition WG

// ---------------- bf16 helpers ----------------

__device__ __forceinline__ unsigned short f2bf(float f) {   // round-to-nearest-even
    union { float f; unsigned u; } c; c.f = f;
    unsigned r = c.u + 0x7fffu + ((c.u >> 16) & 1u);
    return (unsigned short)(r >> 16);
}
__device__ __forceinline__ float bflo(unsigned u) {         // low bf16 -> f32
    union { unsigned u; float f; } c; c.u = u << 16; return c.f;
}
__device__ __forceinline__ float bfhi(unsigned u) {         // high bf16 -> f32
    union { unsigned u; float f; } c; c.u = u & 0xffff0000u; return c.f;
}
__device__ __forceinline__ unsigned pack2(float a, float b) {
    return (unsigned)f2bf(a) | ((unsigned)f2bf(b) << 16);
}

// ================= init: zero bcursor + phantom rows =================

__global__ void init_kernel(unsigned* __restrict__ p, int nz,
                            unsigned* __restrict__ dummyA,
                            unsigned* __restrict__ dummyB) {
    int i = blockIdx.x * blockDim.x + threadIdx.x;
    if (i < nz) p[i] = 0u;
    if (blockIdx.x == 0) {
        int t = threadIdx.x;
        if (t < 32) dummyA[t] = 0u;
        else if (t < 64) dummyB[t - 32] = 0u;
    }
}

// ================= feature fusion =================
// writes bf16 x into totB and dis-premultiplied bf16 y into y0

__global__ void fuse_users_kernel(const float* __restrict__ feat,       // [U,15]
                                  const int* __restrict__ cidx,
                                  const int* __restrict__ sidx,
                                  const float* __restrict__ emb_w,      // [U,64]
                                  const float* __restrict__ Wn,         // [64,12]
                                  const float* __restrict__ bn,
                                  const float* __restrict__ Wv,         // [64,3]
                                  const float* __restrict__ bv,
                                  const float* __restrict__ color_w,    // [22,64]
                                  const float* __restrict__ size_w,     // [18,64]
                                  const float* __restrict__ dis,        // [N]
                                  unsigned short* __restrict__ totB,    // [N,64] bf16
                                  unsigned short* __restrict__ y0,      // [(N+1),64] bf16
                                  int U) {
    int t = blockIdx.x * blockDim.x + threadIdx.x;
    int u = t >> 6, d = t & 63;
    if (u >= U) return;
    const float* f = feat + (size_t)u * 15;
    float acc = emb_w[(size_t)u * EMB + d] + bn[d] + bv[d];
#pragma unroll
    for (int k = 0; k < 12; ++k) acc = fmaf(f[k], Wn[d * 12 + k], acc);
#pragma unroll
    for (int k = 0; k < 3; ++k) acc = fmaf(f[12 + k], Wv[d * 3 + k], acc);
    acc += color_w[(size_t)cidx[u] * EMB + d];
    acc += size_w[(size_t)sidx[u] * EMB + d];
    size_t o = (size_t)u * EMB + d;
    totB[o] = f2bf(acc);
    y0[o] = f2bf(acc * dis[u]);
}

__global__ void fuse_items_kernel(const float* __restrict__ feat,       // [I,17]
                                  const float* __restrict__ emb_w,      // [I,64]
                                  const float* __restrict__ Wn,         // [64,5]
                                  const float* __restrict__ bn,
                                  const float* __restrict__ Wv,         // [64,12]
                                  const float* __restrict__ bv,
                                  const float* __restrict__ dis,        // [N]
                                  unsigned short* __restrict__ totB,
                                  unsigned short* __restrict__ y0,
                                  int I, int U) {
    int t = blockIdx.x * blockDim.x + threadIdx.x;
    int i = t >> 6, d = t & 63;
    if (i >= I) return;
    const float* f = feat + (size_t)i * 17;
    float acc = emb_w[(size_t)i * EMB + d] + bn[d] + bv[d];
#pragma unroll
    for (int k = 0; k < 5; ++k) acc = fmaf(f[k], Wn[d * 5 + k], acc);
#pragma unroll
    for (int k = 0; k < 12; ++k) acc = fmaf(f[5 + k], Wv[d * 12 + k], acc);
    int n = U + i;
    size_t o = (size_t)n * EMB + d;
    totB[o] = f2bf(acc);
    y0[o] = f2bf(acc * dis[n]);
}

// ================= bucketed CSR build =================
// pass 1: partition edges into NB col-range buckets (packed row<<9 | col&511)
// uint4-vectorized edge loads: 4 edges/lane/iter.

__global__ __launch_bounds__(512) void partition_kernel(
        const int* __restrict__ row, const int* __restrict__ col,
        unsigned* __restrict__ bcursor, unsigned* __restrict__ bucketbuf,
        int E, int NB) {
    __shared__ unsigned h[NBMAX];
    __shared__ unsigned wbase[NBMAX];
    const int t = threadIdx.x;
    const long chunk = (long)blockIdx.x * CHUNK;

    for (int i = t; i < NB; i += 512) h[i] = 0u;
    __syncthreads();
    // phase A: histogram
    for (int it = 0; it < CHUNK / 2048; ++it) {
        long e = chunk + (long)it * 2048 + t * 4;
        if (e + 3 < E) {
            uint4 c4 = *reinterpret_cast<const uint4*>(&col[e]);
            atomicAdd(&h[c4.x >> 9], 1u); atomicAdd(&h[c4.y >> 9], 1u);
            atomicAdd(&h[c4.z >> 9], 1u); atomicAdd(&h[c4.w >> 9], 1u);
        } else {
            for (int k = 0; k < 4; ++k) {
                long ek = e + k;
                if (ek < E) atomicAdd(&h[((unsigned)col[ek]) >> 9], 1u);
            }
        }
    }
    __syncthreads();
    // phase B: reserve global space
    for (int i = t; i < NB; i += 512) {
        unsigned c = h[i];
        wbase[i] = c ? atomicAdd(&bcursor[i], c) : 0u;
    }
    __syncthreads();
    for (int i = t; i < NB; i += 512) h[i] = 0u;
    __syncthreads();
    // phase C: scatter packed edges
    for (int it = 0; it < CHUNK / 2048; ++it) {
        long e = chunk + (long)it * 2048 + t * 4;
        if (e + 3 < E) {
            uint4 c4 = *reinterpret_cast<const uint4*>(&col[e]);
            uint4 r4 = *reinterpret_cast<const uint4*>(&row[e]);
            unsigned cs[4] = {c4.x, c4.y, c4.z, c4.w};
            unsigned rs[4] = {r4.x, r4.y, r4.z, r4.w};
#pragma unroll
            for (int k = 0; k < 4; ++k) {
                unsigned b = cs[k] >> 9;
                unsigned pos = wbase[b] + atomicAdd(&h[b], 1u);
                if (pos < BCAP)
                    bucketbuf[(size_t)b * BCAP + pos] = (rs[k] << 9) | (cs[k] & 511u);
            }
        } else {
            for (int k = 0; k < 4; ++k) {
                long ek = e + k;
                if (ek < E) {
                    unsigned c = (unsigned)col[ek];
                    unsigned b = c >> 9;
                    unsigned pos = wbase[b] + atomicAdd(&h[b], 1u);
                    if (pos < BCAP)
                        bucketbuf[(size_t)b * BCAP + pos] =
                            (((unsigned)row[ek]) << 9) | (c & 511u);
                }
            }
        }
    }
}

// pass 2: one 512-thread WG per bucket (1 node/thread) -> meta (pad-8 lists),
// dis, srcidx (pre-shifted word offsets + phantom pads), AND within-bucket
// degree-sorted order[] (buckets are globally dense: only the last is partial)

__global__ __launch_bounds__(512) void bucket_csr_kernel(
        const unsigned* __restrict__ bcursor,
        const unsigned* __restrict__ bucketbuf,
        uint4* __restrict__ meta,               // [N] {beg,end,dis_bits,0}
        float* __restrict__ dis, unsigned* __restrict__ srcidx,
        unsigned* __restrict__ order,           // [N] degree-class-sorted ids
        int N, int NB) {
    const int b = blockIdx.x;
    const int t = threadIdx.x;
    __shared__ unsigned hist[512];
    __shared__ unsigned ps[512];
    __shared__ unsigned cls[64];
    __shared__ unsigned clsB[64];

    const unsigned base = (unsigned)b * BSTRIDE;
    unsigned cntb = bcursor[b];
    if (cntb > BCAP) cntb = BCAP;

    hist[t] = 0u;
    if (t < 64) cls[t] = 0u;
    __syncthreads();
    const unsigned* buf = bucketbuf + (size_t)b * BCAP;
    for (unsigned j = t; j < cntb; j += 512) atomicAdd(&hist[buf[j] & 511u], 1u);
    __syncthreads();

    unsigned h0 = hist[t];
    unsigned c0p = (h0 + 7u) & ~7u;    // pad to multiple of 8
    ps[t] = c0p;
    __syncthreads();
    for (int off = 1; off < 512; off <<= 1) {
        unsigned y = (t >= off) ? ps[t - off] : 0u;
        __syncthreads();
        ps[t] += y;
        __syncthreads();
    }
    unsigned beg0 = base + ps[t] - c0p;

    int n0 = (b << 9) + t;
    unsigned c = min(c0p >> 3, 63u), lpos = 0;
    if (n0 < N) {
        float dv = h0 ? rsqrtf((float)h0) : 0.f;
        meta[n0] = make_uint4(beg0, beg0 + c0p, __float_as_uint(dv), 0u);
        dis[n0] = dv;
        lpos = atomicAdd(&cls[c], 1u);     // rank within class
        for (unsigned k = h0; k < c0p; ++k) srcidx[beg0 + k] = ((unsigned)N) << 5;
    }
    __syncthreads();
    if (t == 0) {   // exclusive scan of the 64 class counts
        unsigned run = 0;
        for (int i = 0; i < 64; ++i) { unsigned v = cls[i]; clsB[i] = run; run += v; }
    }
    __syncthreads();
    if (n0 < N) order[(b << 9) + clsB[c] + lpos] = (unsigned)n0;

    // scatter via LDS cursors; writes stay in one bucket region
    hist[t] = beg0;
    __syncthreads();
    for (unsigned j = t; j < cntb; j += 512) {
        unsigned p = buf[j];
        unsigned pos = atomicAdd(&hist[p & 511u], 1u);
        srcidx[pos] = (p >> 9) << 5;   // u32 word offset of source row
    }
}

// ================= propagation =================
// TWO nodes per wave (degree-sorted), 16-edge unrolled main loop with two
// accumulator banks + one 8-edge tail (lists pad-8). totB read hoisted above
// the loop. mode 0: RMW bf16 totB + store ynext; mode 1 (final layer): write
// f32 out = (tot + a)*0.25 directly (finalize fused).

__global__ __launch_bounds__(256) void gather_propagate_kernel(
        const unsigned* __restrict__ order, const uint4* __restrict__ meta,
        const unsigned* __restrict__ src,   // [(N+1)*32]
        const unsigned* __restrict__ srcidx,
        unsigned* __restrict__ ynext,       // [(N+1)*32]
        unsigned* __restrict__ totB,        // [N*32] bf16x2
        float4* __restrict__ outF,          // [N*16] f32 (mode 1)
        int N, int mode) {
    int lane = threadIdx.x & 63;
    int slot = blockIdx.x * 8 + ((threadIdx.x >> 6) << 1) + (lane >> 5);
    bool active = slot < N;
    int n = active ? (int)order[slot] : 0;
    uint4 md = active ? meta[n] : make_uint4(0u, 0u, 0u, 0u);
    unsigned beg = md.x, endp = md.y;
    float dn = __uint_as_float(md.z);
    unsigned q = (unsigned)((lane >> 4) & 1);
    unsigned m2 = (unsigned)(lane & 15) * 2u;
    size_t o = (size_t)n * 32 + m2;
    uint2 tv = *reinterpret_cast<const uint2*>(&totB[o]);   // hoisted RMW-read
    float s0 = 0.f, s1 = 0.f, s2 = 0.f, s3 = 0.f;
    float t0 = 0.f, t1 = 0.f, t2 = 0.f, t3 = 0.f;
    unsigned j = beg;
    for (; j + 16 <= endp; j += 16) {   // 16 edges/node/iter, 2 chains
        uint4 iv0 = *reinterpret_cast<const uint4*>(&srcidx[j + 4u * q]);
        uint4 iv1 = *reinterpret_cast<const uint4*>(&srcidx[j + 8u + 4u * q]);
        uint2 ua = *reinterpret_cast<const uint2*>(&src[iv0.x + m2]);
        uint2 ub = *reinterpret_cast<const uint2*>(&src[iv0.y + m2]);
        uint2 uc = *reinterpret_cast<const uint2*>(&src[iv0.z + m2]);
        uint2 ud = *reinterpret_cast<const uint2*>(&src[iv0.w + m2]);
        uint2 ue = *reinterpret_cast<const uint2*>(&src[iv1.x + m2]);
        uint2 uf = *reinterpret_cast<const uint2*>(&src[iv1.y + m2]);
        uint2 ug = *reinterpret_cast<const uint2*>(&src[iv1.z + m2]);
        uint2 uh = *reinterpret_cast<const uint2*>(&src[iv1.w + m2]);
        s0 += (bflo(ua.x) + bflo(ub.x)) + (bflo(uc.x) + bflo(ud.x));
        s1 += (bfhi(ua.x) + bfhi(ub.x)) + (bfhi(uc.x) + bfhi(ud.x));
        s2 += (bflo(ua.y) + bflo(ub.y)) + (bflo(uc.y) + bflo(ud.y));
        s3 += (bfhi(ua.y) + bfhi(ub.y)) + (bfhi(uc.y) + bfhi(ud.y));
        t0 += (bflo(ue.x) + bflo(uf.x)) + (bflo(ug.x) + bflo(uh.x));
        t1 += (bfhi(ue.x) + bfhi(uf.x)) + (bfhi(ug.x) + bfhi(uh.x));
        t2 += (bflo(ue.y) + bflo(uf.y)) + (bflo(ug.y) + bflo(uh.y));
        t3 += (bfhi(ue.y) + bfhi(uf.y)) + (bfhi(ug.y) + bfhi(uh.y));
    }
    if (j < endp) {   // exactly one 8-edge tail (pad-8 lists)
        uint4 iv = *reinterpret_cast<const uint4*>(&srcidx[j + 4u * q]);
        uint2 ua = *reinterpret_cast<const uint2*>(&src[iv.x + m2]);
        uint2 ub = *reinterpret_cast<const uint2*>(&src[iv.y + m2]);
        uint2 uc = *reinterpret_cast<const uint2*>(&src[iv.z + m2]);
        uint2 ud = *reinterpret_cast<const uint2*>(&src[iv.w + m2]);
        s0 += (bflo(ua.x) + bflo(ub.x)) + (bflo(uc.x) + bflo(ud.x));
        s1 += (bfhi(ua.x) + bfhi(ub.x)) + (bfhi(uc.x) + bfhi(ud.x));
        s2 += (bflo(ua.y) + bflo(ub.y)) + (bflo(uc.y) + bflo(ud.y));
        s3 += (bfhi(ua.y) + bfhi(ub.y)) + (bfhi(uc.y) + bfhi(ud.y));
    }
    s0 += t0; s1 += t1; s2 += t2; s3 += t3;
    // combine the two q-groups within each half (xor 16 stays inside the half)
    s0 += __shfl_xor(s0, 16);
    s1 += __shfl_xor(s1, 16);
    s2 += __shfl_xor(s2, 16);
    s3 += __shfl_xor(s3, 16);
    if (active && (lane & 31) < 16) {
        float a0 = dn * s0, a1 = dn * s1, a2 = dn * s2, a3 = dn * s3;
        float b0 = bflo(tv.x) + a0, b1 = bfhi(tv.x) + a1;
        float b2 = bflo(tv.y) + a2, b3 = bfhi(tv.y) + a3;
        if (mode == 0) {
            uint2 nv;
            nv.x = pack2(b0, b1);
            nv.y = pack2(b2, b3);
            *reinterpret_cast<uint2*>(&totB[o]) = nv;
            uint2 pk;
            pk.x = pack2(dn * a0, dn * a1);
            pk.y = pack2(dn * a2, dn * a3);
            *reinterpret_cast<uint2*>(&ynext[(size_t)n * 32 + m2]) = pk;
        } else {
            outF[(size_t)n * 16 + (m2 >> 1)] =
                make_float4(b0 * 0.25f, b1 * 0.25f, b2 * 0.25f, b3 * 0.25f);
        }
    }
}

// ================= launch =================

extern "C" void kernel_launch(void* const* d_in, const int* in_sizes, int n_in,
                              void* d_out, int out_size, void* d_ws, size_t ws_size,
                              hipStream_t stream) {
    const int*   edge       = (const int*)d_in[0];
    const float* user_feat  = (const float*)d_in[1];
    const int*   cidx       = (const int*)d_in[2];
    const int*   sidx       = (const int*)d_in[3];
    const float* item_feat  = (const float*)d_in[4];
    const float* user_emb_w = (const float*)d_in[5];
    const float* item_emb_w = (const float*)d_in[6];
    const float* uWn        = (const float*)d_in[7];
    const float* ubn        = (const float*)d_in[8];
    const float* uWv        = (const float*)d_in[9];
    const float* ubv        = (const float*)d_in[10];
    const float* color_w    = (const float*)d_in[11];
    const float* size_w     = (const float*)d_in[12];
    const float* iWn        = (const float*)d_in[13];
    const float* ibn        = (const float*)d_in[14];
    const float* iWv        = (const float*)d_in[15];
    const float* ibv        = (const float*)d_in[16];

    const int E = in_sizes[0] / 2;
    const int U = in_sizes[5] / EMB;
    const int I = in_sizes[6] / EMB;
    const int N = U + I;
    const int NB = (N + 511) >> 9;     // 293 buckets

    const int* row = edge;
    const int* col = edge + E;

    // workspace layout (u32 units)
    unsigned short* yA      = (unsigned short*)d_ws;          // [(N+1)*64] bf16
    unsigned short* yB      = yA + (size_t)(N + 1) * EMB;     // [(N+1)*64] bf16
    unsigned*       bucketbuf = (unsigned*)yB;                // [NB*BCAP] aliases yB
                                                              // (dummy row at word
                                                              // N*32=4.8M > 2.4M cap
                                                              // -> no overlap)
    unsigned short* totB    = yB + (size_t)(N + 1) * EMB;     // [N*64] bf16 running sum
    unsigned*       srcidx  = (unsigned*)(totB + (size_t)N * EMB);      // [NB*BSTRIDE]
    uint4*          meta    = (uint4*)(srcidx + (size_t)NB * BSTRIDE);  // [N]
    float*          dis     = (float*)(meta + N);             // [N]
    unsigned*       bcursor = (unsigned*)(dis + N);           // [NB]
    unsigned*       order   = bcursor + NB;                   // [N]

    const int TB = 256;

    // 1. init (bcursor + phantom rows), then CSR build (+ in-bucket degree sort)
    init_kernel<<<(NB + TB - 1) / TB, TB, 0, stream>>>(
        bcursor, NB,
        (unsigned*)(yA + (size_t)N * EMB), (unsigned*)(yB + (size_t)N * EMB));
    const int gP = (E + CHUNK - 1) / CHUNK;
    partition_kernel<<<gP, 512, 0, stream>>>(row, col, bcursor, bucketbuf, E, NB);
    bucket_csr_kernel<<<NB, 512, 0, stream>>>(bcursor, bucketbuf, meta, dis,
                                              srcidx, order, N, NB);

    // 2. fuse features: totB = bf16(x), yA = bf16(dis*x)
    {
        int gU = (int)(((long)U * EMB + TB - 1) / TB);
        fuse_users_kernel<<<gU, TB, 0, stream>>>(user_feat, cidx, sidx, user_emb_w,
                                                 uWn, ubn, uWv, ubv, color_w, size_w,
                                                 dis, totB, yA, U);
        int gI = (int)(((long)I * EMB + TB - 1) / TB);
        fuse_items_kernel<<<gI, TB, 0, stream>>>(item_feat, item_emb_w,
                                                 iWn, ibn, iWv, ibv,
                                                 dis, totB, yA, I, U);
    }

    // 3. three propagation layers; finalize fused into layer 3 (mode 1)
    const int gG = (N + 7) / 8;   // 8 degree-matched nodes per block (2/wave)
    gather_propagate_kernel<<<gG, TB, 0, stream>>>(order, meta,
                                                   (const unsigned*)yA, srcidx,
                                                   (unsigned*)yB, (unsigned*)totB,
                                                   (float4*)d_out, N, 0);
    gather_propagate_kernel<<<gG, TB, 0, stream>>>(order, meta,
                                                   (const unsigned*)yB, srcidx,
                                                   (unsigned*)yA, (unsigned*)totB,
                                                   (float4*)d_out, N, 0);
    gather_propagate_kernel<<<gG, TB, 0, stream>>>(order, meta,
                                                   (const unsigned*)yA, srcidx,
                                                   (unsigned*)yB, (unsigned*)totB,
                                                   (float4*)d_out, N, 1);

    (void)n_in; (void)out_size; (void)ws_size;
}

// Round 16
// 231.017 us; speedup vs baseline: 2.1854x; 1.0240x over previous
//
#include <hip/hip_runtime.h>

#define EMB 64
#define NBMAX 512      // max buckets (NB = ceil(N/512) = 293 for N=150000)
#define BCAP 8192      // bucket edge capacity (mean 6827, +16 sigma; = 16*512)
#define BSTRIDE 12288  // padded bucket region: BCAP + 512 nodes * 8 pad slots
#define CHUNK 4096     // edges per partition WG

// ---------------- bf16 helpers ----------------

__device__ __forceinline__ unsigned short f2bf(float f) {   // round-to-nearest-even
    union { float f; unsigned u; } c; c.f = f;
    unsigned r = c.u + 0x7fffu + ((c.u >> 16) & 1u);
    return (unsigned short)(r >> 16);
}
__device__ __forceinline__ float bflo(unsigned u) {         // low bf16 -> f32
    union { unsigned u; float f; } c; c.u = u << 16; return c.f;
}
__device__ __forceinline__ float bfhi(unsigned u) {         // high bf16 -> f32
    union { unsigned u; float f; } c; c.u = u & 0xffff0000u; return c.f;
}
__device__ __forceinline__ unsigned pack2(float a, float b) {
    return (unsigned)f2bf(a) | ((unsigned)f2bf(b) << 16);
}

// ================= init: zero bcursor + phantom rows =================

__global__ void init_kernel(unsigned* __restrict__ p, int nz,
                            unsigned* __restrict__ dummyA,
                            unsigned* __restrict__ dummyB) {
    int i = blockIdx.x * blockDim.x + threadIdx.x;
    if (i < nz) p[i] = 0u;
    if (blockIdx.x == 0) {
        int t = threadIdx.x;
        if (t < 32) dummyA[t] = 0u;
        else if (t < 64) dummyB[t - 32] = 0u;
    }
}

// ================= feature fusion (merged, 2 dims/thread) =================
// writes bf16 x into totB and dis-premultiplied bf16 y into y0

__global__ __launch_bounds__(256) void fuse_kernel(
        const float* __restrict__ ufeat,      // [U,15]
        const int* __restrict__ cidx, const int* __restrict__ sidx,
        const float* __restrict__ uemb,       // [U,64]
        const float* __restrict__ uWn, const float* __restrict__ ubn,
        const float* __restrict__ uWv, const float* __restrict__ ubv,
        const float* __restrict__ color_w,    // [22,64]
        const float* __restrict__ size_w,     // [18,64]
        const float* __restrict__ ifeat,      // [I,17]
        const float* __restrict__ iemb,       // [I,64]
        const float* __restrict__ iWn, const float* __restrict__ ibn,
        const float* __restrict__ iWv, const float* __restrict__ ibv,
        const float* __restrict__ dis,        // [N]
        unsigned* __restrict__ totB,          // [N*32] bf16x2
        unsigned* __restrict__ y0,            // [(N+1)*32] bf16x2
        int U, int N) {
    int t = blockIdx.x * blockDim.x + threadIdx.x;
    int n = t >> 5, m = t & 31;
    if (n >= N) return;
    int d0 = m * 2, d1 = d0 + 1;
    float acc0, acc1;
    if (n < U) {
        const float* f = ufeat + (size_t)n * 15;
        float2 e = *reinterpret_cast<const float2*>(&uemb[(size_t)n * EMB + d0]);
        acc0 = e.x + ubn[d0] + ubv[d0];
        acc1 = e.y + ubn[d1] + ubv[d1];
#pragma unroll
        for (int k = 0; k < 12; ++k) {
            float fv = f[k];
            acc0 = fmaf(fv, uWn[d0 * 12 + k], acc0);
            acc1 = fmaf(fv, uWn[d1 * 12 + k], acc1);
        }
#pragma unroll
        for (int k = 0; k < 3; ++k) {
            float fv = f[12 + k];
            acc0 = fmaf(fv, uWv[d0 * 3 + k], acc0);
            acc1 = fmaf(fv, uWv[d1 * 3 + k], acc1);
        }
        float2 cw = *reinterpret_cast<const float2*>(&color_w[(size_t)cidx[n] * EMB + d0]);
        float2 sw = *reinterpret_cast<const float2*>(&size_w[(size_t)sidx[n] * EMB + d0]);
        acc0 += cw.x + sw.x;
        acc1 += cw.y + sw.y;
    } else {
        int i = n - U;
        const float* f = ifeat + (size_t)i * 17;
        float2 e = *reinterpret_cast<const float2*>(&iemb[(size_t)i * EMB + d0]);
        acc0 = e.x + ibn[d0] + ibv[d0];
        acc1 = e.y + ibn[d1] + ibv[d1];
#pragma unroll
        for (int k = 0; k < 5; ++k) {
            float fv = f[k];
            acc0 = fmaf(fv, iWn[d0 * 5 + k], acc0);
            acc1 = fmaf(fv, iWn[d1 * 5 + k], acc1);
        }
#pragma unroll
        for (int k = 0; k < 12; ++k) {
            float fv = f[5 + k];
            acc0 = fmaf(fv, iWv[d0 * 12 + k], acc0);
            acc1 = fmaf(fv, iWv[d1 * 12 + k], acc1);
        }
    }
    float dv = dis[n];
    size_t o = (size_t)n * 32 + m;
    totB[o] = pack2(acc0, acc1);
    y0[o] = pack2(acc0 * dv, acc1 * dv);
}

// ================= bucketed CSR build =================
// pass 1: partition edges into NB col-range buckets (packed row<<9 | col&511)
// cols register-cached between histogram and scatter phases.

__global__ __launch_bounds__(512) void partition_kernel(
        const int* __restrict__ row, const int* __restrict__ col,
        unsigned* __restrict__ bcursor, unsigned* __restrict__ bucketbuf,
        int E, int NB) {
    __shared__ unsigned h[NBMAX];
    __shared__ unsigned wbase[NBMAX];
    const int t = threadIdx.x;
    const long chunk = (long)blockIdx.x * CHUNK;

    for (int i = t; i < NB; i += 512) h[i] = 0u;
    __syncthreads();
    unsigned cc[2][4];
    // phase A: histogram (cols cached in registers)
#pragma unroll
    for (int it = 0; it < 2; ++it) {
        long e = chunk + (long)it * 2048 + (long)t * 4;
        if (e + 3 < (long)E) {
            uint4 c4 = *reinterpret_cast<const uint4*>(&col[e]);
            cc[it][0] = c4.x; cc[it][1] = c4.y; cc[it][2] = c4.z; cc[it][3] = c4.w;
            atomicAdd(&h[c4.x >> 9], 1u); atomicAdd(&h[c4.y >> 9], 1u);
            atomicAdd(&h[c4.z >> 9], 1u); atomicAdd(&h[c4.w >> 9], 1u);
        } else {
#pragma unroll
            for (int k = 0; k < 4; ++k) {
                long ek = e + k;
                unsigned cv = (ek < (long)E) ? (unsigned)col[ek] : 0xffffffffu;
                cc[it][k] = cv;
                if (cv != 0xffffffffu) atomicAdd(&h[cv >> 9], 1u);
            }
        }
    }
    __syncthreads();
    // phase B: reserve global space
    for (int i = t; i < NB; i += 512) {
        unsigned c = h[i];
        wbase[i] = c ? atomicAdd(&bcursor[i], c) : 0u;
    }
    __syncthreads();
    for (int i = t; i < NB; i += 512) h[i] = 0u;
    __syncthreads();
    // phase C: scatter packed edges (cols from registers, rows loaded once)
#pragma unroll
    for (int it = 0; it < 2; ++it) {
        long e = chunk + (long)it * 2048 + (long)t * 4;
        if (e + 3 < (long)E) {
            uint4 r4 = *reinterpret_cast<const uint4*>(&row[e]);
            unsigned rs[4] = {r4.x, r4.y, r4.z, r4.w};
#pragma unroll
            for (int k = 0; k < 4; ++k) {
                unsigned cv = cc[it][k];
                unsigned b = cv >> 9;
                unsigned pos = wbase[b] + atomicAdd(&h[b], 1u);
                if (pos < BCAP)
                    bucketbuf[(size_t)b * BCAP + pos] = (rs[k] << 9) | (cv & 511u);
            }
        } else {
#pragma unroll
            for (int k = 0; k < 4; ++k) {
                long ek = e + k;
                unsigned cv = cc[it][k];
                if (cv != 0xffffffffu) {
                    unsigned b = cv >> 9;
                    unsigned pos = wbase[b] + atomicAdd(&h[b], 1u);
                    if (pos < BCAP)
                        bucketbuf[(size_t)b * BCAP + pos] =
                            (((unsigned)row[ek]) << 9) | (cv & 511u);
                }
            }
        }
    }
}

// pass 2: one 512-thread WG per bucket (1 node/thread). Packed edges are
// register-cached (cntb <= 16*512) across histogram->scatter. Produces meta
// (pad-8), dis, srcidx (pre-shifted + phantom pads), and longest-first
// in-bucket degree-sorted order[].

__global__ __launch_bounds__(512) void bucket_csr_kernel(
        const unsigned* __restrict__ bcursor,
        const unsigned* __restrict__ bucketbuf,
        uint4* __restrict__ meta,               // [N] {beg,end,dis_bits,0}
        float* __restrict__ dis, unsigned* __restrict__ srcidx,
        unsigned* __restrict__ order,           // [N] degree-sorted ids
        int N, int NB) {
    const int b = blockIdx.x;
    const int t = threadIdx.x;
    __shared__ unsigned hist[512];
    __shared__ unsigned ps[512];
    __shared__ unsigned cls[64];
    __shared__ unsigned clsB[64];

    const unsigned base = (unsigned)b * BSTRIDE;
    unsigned cntb = bcursor[b];
    if (cntb > BCAP) cntb = BCAP;

    hist[t] = 0u;
    if (t < 64) cls[t] = 0u;
    __syncthreads();
    const unsigned* buf = bucketbuf + (size_t)b * BCAP;
    unsigned rv[16];
#pragma unroll
    for (int it = 0; it < 16; ++it) {
        unsigned j = (unsigned)t + (unsigned)it * 512u;
        unsigned p = (j < cntb) ? buf[j] : 0xffffffffu;
        rv[it] = p;
        if (p != 0xffffffffu) atomicAdd(&hist[p & 511u], 1u);
    }
    __syncthreads();

    unsigned h0 = hist[t];
    unsigned c0p = (h0 + 7u) & ~7u;    // pad to multiple of 8
    ps[t] = c0p;
    __syncthreads();
    for (int off = 1; off < 512; off <<= 1) {
        unsigned y = (t >= off) ? ps[t - off] : 0u;
        __syncthreads();
        ps[t] += y;
        __syncthreads();
    }
    unsigned beg0 = base + ps[t] - c0p;

    int n0 = (b << 9) + t;
    unsigned c = 63u - min(c0p >> 3, 63u);   // inverted: longest-first
    unsigned lpos = 0;
    if (n0 < N) {
        float dv = h0 ? rsqrtf((float)h0) : 0.f;
        meta[n0] = make_uint4(beg0, beg0 + c0p, __float_as_uint(dv), 0u);
        dis[n0] = dv;
        lpos = atomicAdd(&cls[c], 1u);       // rank within class
        for (unsigned k = h0; k < c0p; ++k) srcidx[beg0 + k] = ((unsigned)N) << 5;
    }
    __syncthreads();
    if (t == 0) {   // exclusive scan of the 64 class counts
        unsigned run = 0;
        for (int i = 0; i < 64; ++i) { unsigned v = cls[i]; clsB[i] = run; run += v; }
    }
    __syncthreads();
    if (n0 < N) order[(b << 9) + clsB[c] + lpos] = (unsigned)n0;

    // scatter from registers via LDS cursors; writes stay in one bucket region
    hist[t] = beg0;
    __syncthreads();
#pragma unroll
    for (int it = 0; it < 16; ++it) {
        unsigned p = rv[it];
        if (p != 0xffffffffu) {
            unsigned pos = atomicAdd(&hist[p & 511u], 1u);
            srcidx[pos] = (p >> 9) << 5;   // u32 word offset of source row
        }
    }
}

// ================= propagation =================
// TWO nodes per wave (degree-sorted, longest-first), 16-edge unrolled main
// loop with two accumulator banks + one 8-edge tail (lists pad-8). totB read
// hoisted. mode 0: RMW bf16 totB + store ynext; mode 1: f32 out*(0.25) fused.

__global__ __launch_bounds__(256) void gather_propagate_kernel(
        const unsigned* __restrict__ order, const uint4* __restrict__ meta,
        const unsigned* __restrict__ src,   // [(N+1)*32]
        const unsigned* __restrict__ srcidx,
        unsigned* __restrict__ ynext,       // [(N+1)*32]
        unsigned* __restrict__ totB,        // [N*32] bf16x2
        float4* __restrict__ outF,          // [N*16] f32 (mode 1)
        int N, int mode) {
    int lane = threadIdx.x & 63;
    int slot = blockIdx.x * 8 + ((threadIdx.x >> 6) << 1) + (lane >> 5);
    bool active = slot < N;
    int n = active ? (int)order[slot] : 0;
    uint4 md = active ? meta[n] : make_uint4(0u, 0u, 0u, 0u);
    unsigned beg = md.x, endp = md.y;
    float dn = __uint_as_float(md.z);
    unsigned q = (unsigned)((lane >> 4) & 1);
    unsigned m2 = (unsigned)(lane & 15) * 2u;
    size_t o = (size_t)n * 32 + m2;
    uint2 tv = *reinterpret_cast<const uint2*>(&totB[o]);   // hoisted RMW-read
    float s0 = 0.f, s1 = 0.f, s2 = 0.f, s3 = 0.f;
    float t0 = 0.f, t1 = 0.f, t2 = 0.f, t3 = 0.f;
    unsigned j = beg;
    for (; j + 16 <= endp; j += 16) {   // 16 edges/node/iter, 2 chains
        uint4 iv0 = *reinterpret_cast<const uint4*>(&srcidx[j + 4u * q]);
        uint4 iv1 = *reinterpret_cast<const uint4*>(&srcidx[j + 8u + 4u * q]);
        uint2 ua = *reinterpret_cast<const uint2*>(&src[iv0.x + m2]);
        uint2 ub = *reinterpret_cast<const uint2*>(&src[iv0.y + m2]);
        uint2 uc = *reinterpret_cast<const uint2*>(&src[iv0.z + m2]);
        uint2 ud = *reinterpret_cast<const uint2*>(&src[iv0.w + m2]);
        uint2 ue = *reinterpret_cast<const uint2*>(&src[iv1.x + m2]);
        uint2 uf = *reinterpret_cast<const uint2*>(&src[iv1.y + m2]);
        uint2 ug = *reinterpret_cast<const uint2*>(&src[iv1.z + m2]);
        uint2 uh = *reinterpret_cast<const uint2*>(&src[iv1.w + m2]);
        s0 += (bflo(ua.x) + bflo(ub.x)) + (bflo(uc.x) + bflo(ud.x));
        s1 += (bfhi(ua.x) + bfhi(ub.x)) + (bfhi(uc.x) + bfhi(ud.x));
        s2 += (bflo(ua.y) + bflo(ub.y)) + (bflo(uc.y) + bflo(ud.y));
        s3 += (bfhi(ua.y) + bfhi(ub.y)) + (bfhi(uc.y) + bfhi(ud.y));
        t0 += (bflo(ue.x) + bflo(uf.x)) + (bflo(ug.x) + bflo(uh.x));
        t1 += (bfhi(ue.x) + bfhi(uf.x)) + (bfhi(ug.x) + bfhi(uh.x));
        t2 += (bflo(ue.y) + bflo(uf.y)) + (bflo(ug.y) + bflo(uh.y));
        t3 += (bfhi(ue.y) + bfhi(uf.y)) + (bfhi(ug.y) + bfhi(uh.y));
    }
    if (j < endp) {   // exactly one 8-edge tail (pad-8 lists)
        uint4 iv = *reinterpret_cast<const uint4*>(&srcidx[j + 4u * q]);
        uint2 ua = *reinterpret_cast<const uint2*>(&src[iv.x + m2]);
        uint2 ub = *reinterpret_cast<const uint2*>(&src[iv.y + m2]);
        uint2 uc = *reinterpret_cast<const uint2*>(&src[iv.z + m2]);
        uint2 ud = *reinterpret_cast<const uint2*>(&src[iv.w + m2]);
        s0 += (bflo(ua.x) + bflo(ub.x)) + (bflo(uc.x) + bflo(ud.x));
        s1 += (bfhi(ua.x) + bfhi(ub.x)) + (bfhi(uc.x) + bfhi(ud.x));
        s2 += (bflo(ua.y) + bflo(ub.y)) + (bflo(uc.y) + bflo(ud.y));
        s3 += (bfhi(ua.y) + bfhi(ub.y)) + (bfhi(uc.y) + bfhi(ud.y));
    }
    s0 += t0; s1 += t1; s2 += t2; s3 += t3;
    // combine the two q-groups within each half (xor 16 stays inside the half)
    s0 += __shfl_xor(s0, 16);
    s1 += __shfl_xor(s1, 16);
    s2 += __shfl_xor(s2, 16);
    s3 += __shfl_xor(s3, 16);
    if (active && (lane & 31) < 16) {
        float a0 = dn * s0, a1 = dn * s1, a2 = dn * s2, a3 = dn * s3;
        float b0 = bflo(tv.x) + a0, b1 = bfhi(tv.x) + a1;
        float b2 = bflo(tv.y) + a2, b3 = bfhi(tv.y) + a3;
        if (mode == 0) {
            uint2 nv;
            nv.x = pack2(b0, b1);
            nv.y = pack2(b2, b3);
            *reinterpret_cast<uint2*>(&totB[o]) = nv;
            uint2 pk;
            pk.x = pack2(dn * a0, dn * a1);
            pk.y = pack2(dn * a2, dn * a3);
            *reinterpret_cast<uint2*>(&ynext[(size_t)n * 32 + m2]) = pk;
        } else {
            outF[(size_t)n * 16 + (m2 >> 1)] =
                make_float4(b0 * 0.25f, b1 * 0.25f, b2 * 0.25f, b3 * 0.25f);
        }
    }
}

// ================= launch =================

extern "C" void kernel_launch(void* const* d_in, const int* in_sizes, int n_in,
                              void* d_out, int out_size, void* d_ws, size_t ws_size,
                              hipStream_t stream) {
    const int*   edge       = (const int*)d_in[0];
    const float* user_feat  = (const float*)d_in[1];
    const int*   cidx       = (const int*)d_in[2];
    const int*   sidx       = (const int*)d_in[3];
    const float* item_feat  = (const float*)d_in[4];
    const float* user_emb_w = (const float*)d_in[5];
    const float* item_emb_w = (const float*)d_in[6];
    const float* uWn        = (const float*)d_in[7];
    const float* ubn        = (const float*)d_in[8];
    const float* uWv        = (const float*)d_in[9];
    const float* ubv        = (const float*)d_in[10];
    const float* color_w    = (const float*)d_in[11];
    const float* size_w     = (const float*)d_in[12];
    const float* iWn        = (const float*)d_in[13];
    const float* ibn        = (const float*)d_in[14];
    const float* iWv        = (const float*)d_in[15];
    const float* ibv        = (const float*)d_in[16];

    const int E = in_sizes[0] / 2;
    const int U = in_sizes[5] / EMB;
    const int I = in_sizes[6] / EMB;
    const int N = U + I;
    const int NB = (N + 511) >> 9;     // 293 buckets

    const int* row = edge;
    const int* col = edge + E;

    // workspace layout (u32 units)
    unsigned short* yA      = (unsigned short*)d_ws;          // [(N+1)*64] bf16
    unsigned short* yB      = yA + (size_t)(N + 1) * EMB;     // [(N+1)*64] bf16
    unsigned*       bucketbuf = (unsigned*)yB;                // [NB*BCAP] aliases yB
                                                              // (dummy row at word
                                                              // N*32=4.8M > 2.4M cap
                                                              // -> no overlap)
    unsigned short* totB    = yB + (size_t)(N + 1) * EMB;     // [N*64] bf16 running sum
    unsigned*       srcidx  = (unsigned*)(totB + (size_t)N * EMB);      // [NB*BSTRIDE]
    uint4*          meta    = (uint4*)(srcidx + (size_t)NB * BSTRIDE);  // [N]
    float*          dis     = (float*)(meta + N);             // [N]
    unsigned*       bcursor = (unsigned*)(dis + N);           // [NB]
    unsigned*       order   = bcursor + NB;                   // [N]

    const int TB = 256;

    // 1. init (bcursor + phantom rows), then CSR build (+ in-bucket degree sort)
    init_kernel<<<(NB + TB - 1) / TB, TB, 0, stream>>>(
        bcursor, NB,
        (unsigned*)(yA + (size_t)N * EMB), (unsigned*)(yB + (size_t)N * EMB));
    const int gP = (E + CHUNK - 1) / CHUNK;
    partition_kernel<<<gP, 512, 0, stream>>>(row, col, bcursor, bucketbuf, E, NB);
    bucket_csr_kernel<<<NB, 512, 0, stream>>>(bcursor, bucketbuf, meta, dis,
                                              srcidx, order, N, NB);

    // 2. fuse features (single kernel, 2 dims/thread): totB = bf16(x), yA = bf16(dis*x)
    {
        long tF = (long)N * 32;
        fuse_kernel<<<(int)((tF + TB - 1) / TB), TB, 0, stream>>>(
            user_feat, cidx, sidx, user_emb_w, uWn, ubn, uWv, ubv,
            color_w, size_w, item_feat, item_emb_w, iWn, ibn, iWv, ibv,
            dis, (unsigned*)totB, (unsigned*)yA, U, N);
    }

    // 3. three propagation layers; finalize fused into layer 3 (mode 1)
    const int gG = (N + 7) / 8;   // 8 degree-matched nodes per block (2/wave)
    gather_propagate_kernel<<<gG, TB, 0, stream>>>(order, meta,
                                                   (const unsigned*)yA, srcidx,
                                                   (unsigned*)yB, (unsigned*)totB,
                                                   (float4*)d_out, N, 0);
    gather_propagate_kernel<<<gG, TB, 0, stream>>>(order, meta,
                                                   (const unsigned*)yB, srcidx,
                                                   (unsigned*)yA, (unsigned*)totB,
                                                   (float4*)d_out, N, 0);
    gather_propagate_kernel<<<gG, TB, 0, stream>>>(order, meta,
                                                   (const unsigned*)yA, srcidx,
                                                   (unsigned*)yB, (unsigned*)totB,
                                                   (float4*)d_out, N, 1);

    (void)n_in; (void)out_size; (void)ws_size;
}